// Round 1
// baseline (1083.999 us; speedup 1.0000x reference)
//
#include <hip/hip_runtime.h>
#include <cstdint>
#include <cstddef>

// LatentNeuralSDE: 100 sequential EM steps, B=32768, LAT=10.
// R4: transpose-free register-resident network. Weights are the MFMA A
// operand (W^T, out-features on M), activations the B operand (batch on N).
// With the k-permutation pi(q,j)=16*(j>>2)+4q+(j&3) folded into the weight
// fragment gathers, each layer's D output (row=4q+r) is directly the next
// layer's B fragment (k=8q+j) in the SAME lane -> zero LDS round-trips,
// zero bank conflicts, z stays in registers across steps. Global noise/out
// become aligned float2 vectors. Hot loop has NO LDS writes and no barriers.

#define B_TOT 32768
#define NSTEP 100
#define MT    64

typedef __attribute__((ext_vector_type(8))) short sh8;
typedef __attribute__((ext_vector_type(4))) float f32x4;
typedef __attribute__((ext_vector_type(2))) float f32x2;
typedef __attribute__((ext_vector_type(4))) unsigned int u32x4;

#define MFMA(a, b, c) __builtin_amdgcn_mfma_f32_16x16x32_bf16((a), (b), (c), 0, 0, 0)

struct __align__(16) Lds {
  union {
    float ar[MT][100];               // encoder outputs [a(64), r(32)] (prologue only)
    struct {
      short w2l[16][64][8];          // W2^T frags t2=4..7, frag-linear (conflict-free)
      float db2l[4][128];            // per-wave copy of db2 (broadcast reads)
    } s;
  } u;
  float tsl[104];
};

static __device__ __forceinline__ short f2bf(float v) {  // RTNE (weights, one-time)
  unsigned u = __builtin_bit_cast(unsigned, v);
  u += 0x7fffu + ((u >> 16) & 1u);
  return (short)(u >> 16);
}
// pack two floats -> (bf16(hi)<<16)|bf16(lo) : 2 adds + 1 v_perm
static __device__ __forceinline__ unsigned pk2(float lo, float hi) {
  unsigned a = __builtin_bit_cast(unsigned, lo) + 0x8000u;
  unsigned b = __builtin_bit_cast(unsigned, hi) + 0x8000u;
  return __builtin_amdgcn_perm(b, a, 0x07060302u);
}
static __device__ __forceinline__ sh8 mk4(unsigned a, unsigned b, unsigned c, unsigned d) {
  return __builtin_bit_cast(sh8, (u32x4){a, b, c, d});
}
static __device__ __forceinline__ float tanh_fast(float x) {
  float e = __builtin_amdgcn_exp2f(x * 2.8853900817779268f);
  float r = __builtin_amdgcn_rcpf(e + 1.0f);
  return __builtin_fmaf(-2.0f, r, 1.0f);
}
static __device__ __forceinline__ float softplus_fast(float x) {
  float e = __builtin_amdgcn_exp2f(x * 1.4426950408889634f);
  float l = __builtin_amdgcn_logf(e + 1.0f) * 0.6931471805599453f;
  return (x > 20.0f) ? x : l;
}

__global__ __launch_bounds__(256, 2)
void sde_kernel(const float* __restrict__ z0, const float* __restrict__ activity,
                const float* __restrict__ rest, const float* __restrict__ ts,
                const float* __restrict__ noise,
                const float* __restrict__ aW1, const float* __restrict__ ab1,
                const float* __restrict__ aW2, const float* __restrict__ ab2,
                const float* __restrict__ rW1, const float* __restrict__ rb1,
                const float* __restrict__ rW2, const float* __restrict__ rb2,
                const float* __restrict__ dW1, const float* __restrict__ db1,
                const float* __restrict__ dW2, const float* __restrict__ db2,
                const float* __restrict__ dW3, const float* __restrict__ db3,
                const float* __restrict__ gW1, const float* __restrict__ gb1,
                const float* __restrict__ gW2, const float* __restrict__ gb2,
                float* __restrict__ out)
{
  __shared__ Lds lds;
  const int tid  = threadIdx.x;
  const int lane = tid & 63;
  const int wave = tid >> 6;
  const int n    = lane & 15;   // batch col (B/D) / out-feature row m (A builds)
  const int quad = lane >> 4;
  const int slab = wave * 16;
  const int mblk = blockIdx.x * MT;
  const int rowg = mblk + slab + n;   // this lane's global batch row

  if (tid < 101) lds.tsl[tid] = ts[tid];
  float tcur = ts[0];

  // ---------------- encoders -> ar (wave-private rows: tid>>2 in [16w,16w+16)) ----
  {
    const int e = tid >> 2, p = tid & 3;
    const int eg = mblk + e;
    float act[6], rst[3];
    #pragma unroll
    for (int i = 0; i < 6; ++i) act[i] = activity[eg * 6 + i];
    #pragma unroll
    for (int i = 0; i < 3; ++i) rst[i] = rest[eg * 3 + i];
    float ha[32];
    for (int j = 0; j < 32; ++j) {
      float s = ab1[j];
      #pragma unroll
      for (int i = 0; i < 6; ++i) s = __builtin_fmaf(act[i], aW1[i * 32 + j], s);
      ha[j] = fmaxf(s, 0.0f);
    }
    float hr[16];
    for (int j = 0; j < 16; ++j) {
      float s = rb1[j];
      #pragma unroll
      for (int i = 0; i < 3; ++i) s = __builtin_fmaf(rst[i], rW1[i * 16 + j], s);
      hr[j] = fmaxf(s, 0.0f);
    }
    for (int oo = 0; oo < 24; ++oo) {
      int o = p * 24 + oo;
      float v;
      if (o < 64) {
        v = ab2[o];
        for (int j = 0; j < 32; ++j) v = __builtin_fmaf(ha[j], aW2[j * 64 + o], v);
      } else {
        int ro = o - 64;
        v = rb2[ro];
        for (int j = 0; j < 16; ++j) v = __builtin_fmaf(hr[j], rW2[j * 32 + ro], v);
      }
      lds.u.ar[e][o] = v;
    }
  }
  // no barrier needed: each wave reads only its own 16 ar rows below.

  // ---------------- c1 context fold: c1[batch n][feat 16t+4q+r] ----------------
  f32x4 c1v[8];
  #pragma unroll
  for (int t = 0; t < 8; ++t)
    c1v[t] = *(const f32x4*)(db1 + t * 16 + quad * 4);
  for (int k = 0; k < 96; ++k) {
    float av = lds.u.ar[slab + n][k];
    #pragma unroll
    for (int t = 0; t < 8; ++t) {
      f32x4 w = *(const f32x4*)(dW1 + (10 + k) * 128 + t * 16 + quad * 4);
      #pragma unroll
      for (int r = 0; r < 4; ++r) c1v[t][r] = __builtin_fmaf(av, w[r], c1v[t][r]);
    }
  }
  __syncthreads();   // ar dead everywhere; w2l/db2l (union) may now be written.

  // ---------------- weight A-frags (W^T, pi-permuted k) ----------------
  // pi: slot (quad,j) -> feature fbase + 16*(j>>2) + 4*quad + (j&3)
  sh8 w1za[8];                     // L1 z-part: K=16 real (j>=4 zero)
  #pragma unroll
  for (int t = 0; t < 8; ++t) {
    short tmp[8];
    #pragma unroll
    for (int j = 0; j < 8; ++j) {
      float v = 0.0f;
      if (j < 4) {
        int f = 4 * quad + j;
        if (f < 10) v = dW1[f * 128 + t * 16 + n];
        else if (f == 10) v = dW1[106 * 128 + t * 16 + n];
      }
      tmp[j] = f2bf(v);
    }
    w1za[t] = (sh8){tmp[0],tmp[1],tmp[2],tmp[3],tmp[4],tmp[5],tmp[6],tmp[7]};
  }
  sh8 w2a[4][4];                   // W2^T t2=0..3 in regs, t2=4..7 -> LDS
  #pragma unroll
  for (int t2 = 0; t2 < 8; ++t2) {
    #pragma unroll
    for (int kt = 0; kt < 4; ++kt) {
      short tmp[8];
      #pragma unroll
      for (int j = 0; j < 8; ++j) {
        int f = 32 * kt + 16 * (j >> 2) + 4 * quad + (j & 3);
        tmp[j] = f2bf(dW2[f * 128 + t2 * 16 + n]);
      }
      sh8 fr = (sh8){tmp[0],tmp[1],tmp[2],tmp[3],tmp[4],tmp[5],tmp[6],tmp[7]};
      if (t2 < 4) w2a[t2][kt] = fr;
      else *(sh8*)&lds.u.s.w2l[(t2 - 4) * 4 + kt][lane][0] = fr;
    }
  }
  sh8 w3a[4];                      // W3^T: rows m>=10 zeroed
  #pragma unroll
  for (int kt = 0; kt < 4; ++kt) {
    short tmp[8];
    #pragma unroll
    for (int j = 0; j < 8; ++j) {
      int f = 32 * kt + 16 * (j >> 2) + 4 * quad + (j & 3);
      tmp[j] = f2bf((n < 10) ? dW3[f * 10 + n] : 0.0f);
    }
    w3a[kt] = (sh8){tmp[0],tmp[1],tmp[2],tmp[3],tmp[4],tmp[5],tmp[6],tmp[7]};
  }
  sh8 g1a[2];                      // G1^T: K=16 real
  #pragma unroll
  for (int t = 0; t < 2; ++t) {
    short tmp[8];
    #pragma unroll
    for (int j = 0; j < 8; ++j) {
      float v = 0.0f;
      if (j < 4) {
        int f = 4 * quad + j;
        if (f < 10) v = gW1[f * 32 + t * 16 + n];
        else if (f == 10) v = gW1[10 * 32 + t * 16 + n];
      }
      tmp[j] = f2bf(v);
    }
    g1a[t] = (sh8){tmp[0],tmp[1],tmp[2],tmp[3],tmp[4],tmp[5],tmp[6],tmp[7]};
  }
  sh8 g2a;                         // G2^T: K=32 (both halves real)
  {
    short tmp[8];
    #pragma unroll
    for (int j = 0; j < 8; ++j) {
      int h = 16 * (j >> 2) + 4 * quad + (j & 3);
      tmp[j] = f2bf((n < 10) ? gW2[h * 10 + n] : 0.0f);
    }
    g2a = (sh8){tmp[0],tmp[1],tmp[2],tmp[3],tmp[4],tmp[5],tmp[6],tmp[7]};
  }
  // per-wave db2 copy (wave-private write+read; broadcast-read in loop)
  lds.u.s.db2l[wave][lane]      = db2[lane];
  lds.u.s.db2l[wave][lane + 64] = db2[lane + 64];

  // ---------------- biases in D layout (row = 4q + r) ----------------
  f32x4 cd3v, cg1v0, cg1v1, cg2v;
  #pragma unroll
  for (int r = 0; r < 4; ++r) {
    int o = quad * 4 + r;
    cd3v[r]  = (o < 10) ? db3[o] : 0.0f;
    cg1v0[r] = gb1[o];
    cg1v1[r] = gb1[16 + o];
    cg2v[r]  = (o < 10) ? gb2[o] : 0.0f;
  }

  // ---------------- z init (registers, D layout), out[0] ----------------
  float zreg[4] = {0.0f, 0.0f, 0.0f, 0.0f};
  {
    const float* zp = z0 + (size_t)rowg * 10 + quad * 4;
    float* o0 = out + (size_t)rowg * 10 + quad * 4;
    if (quad < 2) {
      f32x2 a = *(const f32x2*)zp, b = *(const f32x2*)(zp + 2);
      zreg[0] = a.x; zreg[1] = a.y; zreg[2] = b.x; zreg[3] = b.y;
      *(f32x2*)o0 = a; *(f32x2*)(o0 + 2) = b;
    } else if (quad == 2) {
      f32x2 a = *(const f32x2*)zp;
      zreg[0] = a.x; zreg[1] = a.y;
      *(f32x2*)o0 = a;
      zreg[2] = tcur;               // feature 10 = t; feature 11 stays 0
    }
  }
  const float* np = noise + (size_t)rowg * 10 + quad * 4;
  float*       op = out + (size_t)B_TOT * 10 + (size_t)rowg * 10 + quad * 4;

  #pragma unroll 1
  for (int s = 0; s < NSTEP; ++s) {
    float tnext = lds.tsl[s + 1];
    float dtv   = tnext - tcur;
    float sdt   = __builtin_amdgcn_sqrtf(dtv);

    // noise prefetch (vector, used at step end)
    float eps0 = 0.0f, eps1 = 0.0f, eps2 = 0.0f, eps3 = 0.0f;
    if (quad < 2) {
      f32x2 a = *(const f32x2*)np, b = *(const f32x2*)(np + 2);
      eps0 = a.x; eps1 = a.y; eps2 = b.x; eps3 = b.y;
    } else if (quad == 2) {
      f32x2 a = *(const f32x2*)np;
      eps0 = a.x; eps1 = a.y;
    }
    np += (size_t)B_TOT * 10;

    // z B-frag (k = 4q + r via pi; upper half zero-weighted)
    sh8 zf = mk4(pk2(zreg[0], zreg[1]), pk2(zreg[2], zreg[3]), 0u, 0u);

    // ---- diffusion: hg = softplus(zt @ G1), accf = hg @ G2 ----
    f32x4 accf;
    {
      f32x4 g0 = MFMA(g1a[0], zf, cg1v0);
      f32x4 g1 = MFMA(g1a[1], zf, cg1v1);
      sh8 gb = mk4(pk2(softplus_fast(g0[0]), softplus_fast(g0[1])),
                   pk2(softplus_fast(g0[2]), softplus_fast(g0[3])),
                   pk2(softplus_fast(g1[0]), softplus_fast(g1[1])),
                   pk2(softplus_fast(g1[2]), softplus_fast(g1[3])));
      accf = MFMA(g2a, gb, cg2v);
    }

    // ---- drift L1: h1 = tanh(zt @ W1z + c1) -> B-frags in regs ----
    sh8 h1f[4];
    #pragma unroll
    for (int kt = 0; kt < 4; ++kt) {
      f32x4 ae = MFMA(w1za[2 * kt],     zf, c1v[2 * kt]);
      f32x4 ao = MFMA(w1za[2 * kt + 1], zf, c1v[2 * kt + 1]);
      h1f[kt] = mk4(pk2(tanh_fast(ae[0]), tanh_fast(ae[1])),
                    pk2(tanh_fast(ae[2]), tanh_fast(ae[3])),
                    pk2(tanh_fast(ao[0]), tanh_fast(ao[1])),
                    pk2(tanh_fast(ao[2]), tanh_fast(ao[3])));
    }

    // ---- drift L2: h2 = tanh(h1 @ W2 + db2), two halves to cap live accs ----
    sh8 h2f[4];
    {
      f32x4 a2[4];
      #pragma unroll
      for (int t2 = 0; t2 < 4; ++t2) {
        f32x4 acc = *(const f32x4*)&lds.u.s.db2l[wave][t2 * 16 + quad * 4];
        #pragma unroll
        for (int kt = 0; kt < 4; ++kt)
          acc = MFMA(w2a[t2][kt], h1f[kt], acc);
        a2[t2] = acc;
      }
      h2f[0] = mk4(pk2(tanh_fast(a2[0][0]), tanh_fast(a2[0][1])),
                   pk2(tanh_fast(a2[0][2]), tanh_fast(a2[0][3])),
                   pk2(tanh_fast(a2[1][0]), tanh_fast(a2[1][1])),
                   pk2(tanh_fast(a2[1][2]), tanh_fast(a2[1][3])));
      h2f[1] = mk4(pk2(tanh_fast(a2[2][0]), tanh_fast(a2[2][1])),
                   pk2(tanh_fast(a2[2][2]), tanh_fast(a2[2][3])),
                   pk2(tanh_fast(a2[3][0]), tanh_fast(a2[3][1])),
                   pk2(tanh_fast(a2[3][2]), tanh_fast(a2[3][3])));
    }
    {
      f32x4 a2[4];
      #pragma unroll
      for (int t2 = 0; t2 < 4; ++t2) {
        f32x4 acc = *(const f32x4*)&lds.u.s.db2l[wave][(t2 + 4) * 16 + quad * 4];
        #pragma unroll
        for (int kt = 0; kt < 4; ++kt) {
          sh8 wb = *(const sh8*)&lds.u.s.w2l[t2 * 4 + kt][lane][0];
          acc = MFMA(wb, h1f[kt], acc);
        }
        a2[t2] = acc;
      }
      h2f[2] = mk4(pk2(tanh_fast(a2[0][0]), tanh_fast(a2[0][1])),
                   pk2(tanh_fast(a2[0][2]), tanh_fast(a2[0][3])),
                   pk2(tanh_fast(a2[1][0]), tanh_fast(a2[1][1])),
                   pk2(tanh_fast(a2[1][2]), tanh_fast(a2[1][3])));
      h2f[3] = mk4(pk2(tanh_fast(a2[2][0]), tanh_fast(a2[2][1])),
                   pk2(tanh_fast(a2[2][2]), tanh_fast(a2[2][3])),
                   pk2(tanh_fast(a2[3][0]), tanh_fast(a2[3][1])),
                   pk2(tanh_fast(a2[3][2]), tanh_fast(a2[3][3])));
    }

    // ---- drift L3 ----
    f32x4 accd = cd3v;
    #pragma unroll
    for (int kt = 0; kt < 4; ++kt)
      accd = MFMA(w3a[kt], h2f[kt], accd);

    // ---- EM update + vector store ----
    {
      float f0 = accf[0] * sdt, f1 = accf[1] * sdt;
      float f2 = accf[2] * sdt, f3 = accf[3] * sdt;
      zreg[0] = __builtin_fmaf(f0, eps0, __builtin_fmaf(accd[0], dtv, zreg[0]));
      zreg[1] = __builtin_fmaf(f1, eps1, __builtin_fmaf(accd[1], dtv, zreg[1]));
      zreg[2] = __builtin_fmaf(f2, eps2, __builtin_fmaf(accd[2], dtv, zreg[2]));
      zreg[3] = __builtin_fmaf(f3, eps3, __builtin_fmaf(accd[3], dtv, zreg[3]));
    }
    if (quad < 2) {
      *(f32x2*)op       = (f32x2){zreg[0], zreg[1]};
      *(f32x2*)(op + 2) = (f32x2){zreg[2], zreg[3]};
    } else if (quad == 2) {
      *(f32x2*)op       = (f32x2){zreg[0], zreg[1]};
    }
    op += (size_t)B_TOT * 10;
    zreg[2] = (quad == 2) ? tnext : zreg[2];   // refresh t feature
    tcur = tnext;
  }
}

extern "C" void kernel_launch(void* const* d_in, const int* in_sizes, int n_in,
                              void* d_out, int out_size, void* d_ws, size_t ws_size,
                              hipStream_t stream) {
  (void)in_sizes; (void)n_in; (void)d_ws; (void)ws_size; (void)out_size;
  const float* z0       = (const float*)d_in[0];
  const float* activity = (const float*)d_in[1];
  const float* rest     = (const float*)d_in[2];
  const float* ts       = (const float*)d_in[3];
  const float* noise    = (const float*)d_in[4];
  const float* aW1 = (const float*)d_in[5];
  const float* ab1 = (const float*)d_in[6];
  const float* aW2 = (const float*)d_in[7];
  const float* ab2 = (const float*)d_in[8];
  const float* rW1 = (const float*)d_in[9];
  const float* rb1 = (const float*)d_in[10];
  const float* rW2 = (const float*)d_in[11];
  const float* rb2 = (const float*)d_in[12];
  const float* dW1 = (const float*)d_in[13];
  const float* db1 = (const float*)d_in[14];
  const float* dW2 = (const float*)d_in[15];
  const float* db2 = (const float*)d_in[16];
  const float* dW3 = (const float*)d_in[17];
  const float* db3 = (const float*)d_in[18];
  const float* gW1 = (const float*)d_in[19];
  const float* gb1 = (const float*)d_in[20];
  const float* gW2 = (const float*)d_in[21];
  const float* gb2 = (const float*)d_in[22];
  float* out = (float*)d_out;

  dim3 grid(B_TOT / MT), block(256);
  sde_kernel<<<grid, block, 0, stream>>>(
      z0, activity, rest, ts, noise,
      aW1, ab1, aW2, ab2, rW1, rb1, rW2, rb2,
      dW1, db1, dW2, db2, dW3, db3,
      gW1, gb1, gW2, gb2, out);
}

// Round 2
// 1070.189 us; speedup vs baseline: 1.0129x; 1.0129x over previous
//
#include <hip/hip_runtime.h>
#include <cstdint>
#include <cstddef>

// LatentNeuralSDE: 100 sequential EM steps, B=32768, LAT=10.
// R5: transpose-free register-resident network (R4 dataflow) with weight
// fragments in frag-linear LDS to kill the R4 scratch-spill (FETCH 1.74GB
// -> spills of step-invariant frags). Weights are the MFMA A operand (W^T,
// out-features on M), activations the B operand (batch on N). k-permutation
// pi(q,j)=16*(j>>2)+4q+(j&3) folded into weight gathers makes each layer's
// D output directly the next layer's B fragment in the same lane -> no
// transposes, no barriers, no activation LDS traffic. Step-invariant frag
// reads (48/step/wave, conflict-free contiguous 1KB) have no deps and hide
// under compute. Register budget ~96 persistent + ~90 transient << 256.

#define B_TOT 32768
#define NSTEP 100
#define MT    64

typedef __attribute__((ext_vector_type(8))) short sh8;
typedef __attribute__((ext_vector_type(4))) float f32x4;
typedef __attribute__((ext_vector_type(2))) float f32x2;
typedef __attribute__((ext_vector_type(4))) unsigned int u32x4;

#define MFMA(a, b, c) __builtin_amdgcn_mfma_f32_16x16x32_bf16((a), (b), (c), 0, 0, 0)

// fragment table layout in LDS
#define W1F 0            // 8 frags  (L1 z-part, t=0..7)
#define G1F 8            // 2 frags
#define G2F 10           // 1 frag
#define W2F 11           // 24 frags (t2=2..7): W2F + (t2-2)*4 + kt
#define W3F 35           // 4 frags
#define NFR 39

struct __align__(16) Lds {
  union {
    float ar[MT][100];               // encoder outputs (prologue only)
    struct {
      short wfr[NFR][64][8];         // frag-linear weight frags (conflict-free)
      float db2l[4][128];            // per-wave db2 copy (broadcast reads)
    } s;
  } u;                               // 41984 B
  float tsl[104];
};

static __device__ __forceinline__ short f2bf(float v) {  // RTNE (weights, one-time)
  unsigned u = __builtin_bit_cast(unsigned, v);
  u += 0x7fffu + ((u >> 16) & 1u);
  return (short)(u >> 16);
}
// pack two floats -> (bf16(hi)<<16)|bf16(lo) : 2 adds + 1 v_perm
static __device__ __forceinline__ unsigned pk2(float lo, float hi) {
  unsigned a = __builtin_bit_cast(unsigned, lo) + 0x8000u;
  unsigned b = __builtin_bit_cast(unsigned, hi) + 0x8000u;
  return __builtin_amdgcn_perm(b, a, 0x07060302u);
}
static __device__ __forceinline__ sh8 mk4(unsigned a, unsigned b, unsigned c, unsigned d) {
  return __builtin_bit_cast(sh8, (u32x4){a, b, c, d});
}
static __device__ __forceinline__ float tanh_fast(float x) {
  float e = __builtin_amdgcn_exp2f(x * 2.8853900817779268f);
  float r = __builtin_amdgcn_rcpf(e + 1.0f);
  return __builtin_fmaf(-2.0f, r, 1.0f);
}
static __device__ __forceinline__ float softplus_fast(float x) {
  float e = __builtin_amdgcn_exp2f(x * 1.4426950408889634f);
  float l = __builtin_amdgcn_logf(e + 1.0f) * 0.6931471805599453f;
  return (x > 20.0f) ? x : l;
}

__global__ __launch_bounds__(256, 2)
void sde_kernel(const float* __restrict__ z0, const float* __restrict__ activity,
                const float* __restrict__ rest, const float* __restrict__ ts,
                const float* __restrict__ noise,
                const float* __restrict__ aW1, const float* __restrict__ ab1,
                const float* __restrict__ aW2, const float* __restrict__ ab2,
                const float* __restrict__ rW1, const float* __restrict__ rb1,
                const float* __restrict__ rW2, const float* __restrict__ rb2,
                const float* __restrict__ dW1, const float* __restrict__ db1,
                const float* __restrict__ dW2, const float* __restrict__ db2,
                const float* __restrict__ dW3, const float* __restrict__ db3,
                const float* __restrict__ gW1, const float* __restrict__ gb1,
                const float* __restrict__ gW2, const float* __restrict__ gb2,
                float* __restrict__ out)
{
  __shared__ Lds lds;
  const int tid  = threadIdx.x;
  const int lane = tid & 63;
  const int wave = tid >> 6;
  const int n    = lane & 15;   // batch col (B/D col) / A-row m in weight gathers
  const int quad = lane >> 4;
  const int slab = wave * 16;
  const int mblk = blockIdx.x * MT;
  const int rowg = mblk + slab + n;   // this lane's global batch row

  if (tid < 101) lds.tsl[tid] = ts[tid];
  float tcur = ts[0];

  // ---------------- encoders -> ar (wave-private rows) ----------------
  {
    const int e = tid >> 2, p = tid & 3;
    const int eg = mblk + e;
    float act[6], rst[3];
    #pragma unroll
    for (int i = 0; i < 6; ++i) act[i] = activity[eg * 6 + i];
    #pragma unroll
    for (int i = 0; i < 3; ++i) rst[i] = rest[eg * 3 + i];
    float ha[32];
    for (int j = 0; j < 32; ++j) {
      float s = ab1[j];
      #pragma unroll
      for (int i = 0; i < 6; ++i) s = __builtin_fmaf(act[i], aW1[i * 32 + j], s);
      ha[j] = fmaxf(s, 0.0f);
    }
    float hr[16];
    for (int j = 0; j < 16; ++j) {
      float s = rb1[j];
      #pragma unroll
      for (int i = 0; i < 3; ++i) s = __builtin_fmaf(rst[i], rW1[i * 16 + j], s);
      hr[j] = fmaxf(s, 0.0f);
    }
    for (int oo = 0; oo < 24; ++oo) {
      int o = p * 24 + oo;
      float v;
      if (o < 64) {
        v = ab2[o];
        for (int j = 0; j < 32; ++j) v = __builtin_fmaf(ha[j], aW2[j * 64 + o], v);
      } else {
        int ro = o - 64;
        v = rb2[ro];
        for (int j = 0; j < 16; ++j) v = __builtin_fmaf(hr[j], rW2[j * 32 + ro], v);
      }
      lds.u.ar[e][o] = v;
    }
  }
  // no barrier needed: each wave reads only its own 16 ar rows below.

  // ---------------- c1 context fold: c1[batch n][feat 16t+4q+r] ----------------
  f32x4 c1v[8];
  #pragma unroll
  for (int t = 0; t < 8; ++t)
    c1v[t] = *(const f32x4*)(db1 + t * 16 + quad * 4);
  for (int k = 0; k < 96; ++k) {
    float av = lds.u.ar[slab + n][k];
    #pragma unroll
    for (int t = 0; t < 8; ++t) {
      f32x4 w = *(const f32x4*)(dW1 + (10 + k) * 128 + t * 16 + quad * 4);
      #pragma unroll
      for (int r = 0; r < 4; ++r) c1v[t][r] = __builtin_fmaf(av, w[r], c1v[t][r]);
    }
  }
  __syncthreads();   // ar dead everywhere; wfr/db2l (union) may now be written.

  // ---------------- weight A-frags (W^T, pi-permuted k) -> LDS ----------------
  // pi: slot (quad,j) -> feature fbase + 16*(j>>2) + 4*quad + (j&3)
  // All waves write identical per-lane data; duplicate writes are benign and
  // each wave's own writes are visible to it in-order (no barrier needed).
  #pragma unroll
  for (int t = 0; t < 8; ++t) {            // L1 z-part: K=16 real (j>=4 zero)
    short tmp[8];
    #pragma unroll
    for (int j = 0; j < 8; ++j) {
      float v = 0.0f;
      if (j < 4) {
        int f = 4 * quad + j;
        if (f < 10) v = dW1[f * 128 + t * 16 + n];
        else if (f == 10) v = dW1[106 * 128 + t * 16 + n];
      }
      tmp[j] = f2bf(v);
    }
    *(sh8*)&lds.u.s.wfr[W1F + t][lane][0] =
        (sh8){tmp[0],tmp[1],tmp[2],tmp[3],tmp[4],tmp[5],tmp[6],tmp[7]};
  }
  sh8 w2a[2][4];                           // W2^T t2=0..1 in regs, t2=2..7 -> LDS
  #pragma unroll
  for (int t2 = 0; t2 < 8; ++t2) {
    #pragma unroll
    for (int kt = 0; kt < 4; ++kt) {
      short tmp[8];
      #pragma unroll
      for (int j = 0; j < 8; ++j) {
        int f = 32 * kt + 16 * (j >> 2) + 4 * quad + (j & 3);
        tmp[j] = f2bf(dW2[f * 128 + t2 * 16 + n]);
      }
      sh8 fr = (sh8){tmp[0],tmp[1],tmp[2],tmp[3],tmp[4],tmp[5],tmp[6],tmp[7]};
      if (t2 < 2) w2a[t2][kt] = fr;
      else *(sh8*)&lds.u.s.wfr[W2F + (t2 - 2) * 4 + kt][lane][0] = fr;
    }
  }
  #pragma unroll
  for (int kt = 0; kt < 4; ++kt) {         // W3^T: rows m>=10 zeroed
    short tmp[8];
    #pragma unroll
    for (int j = 0; j < 8; ++j) {
      int f = 32 * kt + 16 * (j >> 2) + 4 * quad + (j & 3);
      tmp[j] = f2bf((n < 10) ? dW3[f * 10 + n] : 0.0f);
    }
    *(sh8*)&lds.u.s.wfr[W3F + kt][lane][0] =
        (sh8){tmp[0],tmp[1],tmp[2],tmp[3],tmp[4],tmp[5],tmp[6],tmp[7]};
  }
  #pragma unroll
  for (int t = 0; t < 2; ++t) {            // G1^T: K=16 real
    short tmp[8];
    #pragma unroll
    for (int j = 0; j < 8; ++j) {
      float v = 0.0f;
      if (j < 4) {
        int f = 4 * quad + j;
        if (f < 10) v = gW1[f * 32 + t * 16 + n];
        else if (f == 10) v = gW1[10 * 32 + t * 16 + n];
      }
      tmp[j] = f2bf(v);
    }
    *(sh8*)&lds.u.s.wfr[G1F + t][lane][0] =
        (sh8){tmp[0],tmp[1],tmp[2],tmp[3],tmp[4],tmp[5],tmp[6],tmp[7]};
  }
  {                                        // G2^T: K=32 (both halves real)
    short tmp[8];
    #pragma unroll
    for (int j = 0; j < 8; ++j) {
      int h = 16 * (j >> 2) + 4 * quad + (j & 3);
      tmp[j] = f2bf((n < 10) ? gW2[h * 10 + n] : 0.0f);
    }
    *(sh8*)&lds.u.s.wfr[G2F][lane][0] =
        (sh8){tmp[0],tmp[1],tmp[2],tmp[3],tmp[4],tmp[5],tmp[6],tmp[7]};
  }
  // per-wave db2 copy (wave-private; broadcast-read in loop)
  lds.u.s.db2l[wave][lane]      = db2[lane];
  lds.u.s.db2l[wave][lane + 64] = db2[lane + 64];

  // ---------------- biases in D layout (row = 4q + r) ----------------
  f32x4 cd3v, cg1v0, cg1v1, cg2v;
  #pragma unroll
  for (int r = 0; r < 4; ++r) {
    int o = quad * 4 + r;
    cd3v[r]  = (o < 10) ? db3[o] : 0.0f;
    cg1v0[r] = gb1[o];
    cg1v1[r] = gb1[16 + o];
    cg2v[r]  = (o < 10) ? gb2[o] : 0.0f;
  }

  // ---------------- z init (registers, D layout), out[0] ----------------
  float zreg[4] = {0.0f, 0.0f, 0.0f, 0.0f};
  {
    const float* zp = z0 + (size_t)rowg * 10 + quad * 4;
    float* o0 = out + (size_t)rowg * 10 + quad * 4;
    if (quad < 2) {
      f32x2 a = *(const f32x2*)zp, b = *(const f32x2*)(zp + 2);
      zreg[0] = a.x; zreg[1] = a.y; zreg[2] = b.x; zreg[3] = b.y;
      *(f32x2*)o0 = a; *(f32x2*)(o0 + 2) = b;
    } else if (quad == 2) {
      f32x2 a = *(const f32x2*)zp;
      zreg[0] = a.x; zreg[1] = a.y;
      *(f32x2*)o0 = a;
      zreg[2] = tcur;               // feature 10 = t; feature 11 stays 0
    }
  }
  const float* np = noise + (size_t)rowg * 10 + quad * 4;
  float*       op = out + (size_t)B_TOT * 10 + (size_t)rowg * 10 + quad * 4;

  #pragma unroll 1
  for (int s = 0; s < NSTEP; ++s) {
    float tnext = lds.tsl[s + 1];
    float dtv   = tnext - tcur;
    float sdt   = __builtin_amdgcn_sqrtf(dtv);

    // noise prefetch (vector, used at step end)
    float eps0 = 0.0f, eps1 = 0.0f, eps2 = 0.0f, eps3 = 0.0f;
    if (quad < 2) {
      f32x2 a = *(const f32x2*)np, b = *(const f32x2*)(np + 2);
      eps0 = a.x; eps1 = a.y; eps2 = b.x; eps3 = b.y;
    } else if (quad == 2) {
      f32x2 a = *(const f32x2*)np;
      eps0 = a.x; eps1 = a.y;
    }
    np += (size_t)B_TOT * 10;

    // step-invariant frag reloads (no upstream deps -> latency hidden)
    sh8 w1v[8];
    #pragma unroll
    for (int t = 0; t < 8; ++t)
      w1v[t] = *(const sh8*)&lds.u.s.wfr[W1F + t][lane][0];
    sh8 g1v0 = *(const sh8*)&lds.u.s.wfr[G1F + 0][lane][0];
    sh8 g1v1 = *(const sh8*)&lds.u.s.wfr[G1F + 1][lane][0];
    sh8 g2v  = *(const sh8*)&lds.u.s.wfr[G2F][lane][0];

    // z B-frag (k = 4q + r via pi; upper half zero-weighted)
    sh8 zf = mk4(pk2(zreg[0], zreg[1]), pk2(zreg[2], zreg[3]), 0u, 0u);

    // ---- diffusion: hg = softplus(zt @ G1), accf = hg @ G2 ----
    f32x4 accf;
    {
      f32x4 g0 = MFMA(g1v0, zf, cg1v0);
      f32x4 g1 = MFMA(g1v1, zf, cg1v1);
      sh8 gb = mk4(pk2(softplus_fast(g0[0]), softplus_fast(g0[1])),
                   pk2(softplus_fast(g0[2]), softplus_fast(g0[3])),
                   pk2(softplus_fast(g1[0]), softplus_fast(g1[1])),
                   pk2(softplus_fast(g1[2]), softplus_fast(g1[3])));
      accf = MFMA(g2v, gb, cg2v);
    }

    // ---- drift L1: h1 = tanh(zt @ W1z + c1) -> B-frags in regs ----
    sh8 h1f[4];
    #pragma unroll
    for (int kt = 0; kt < 4; ++kt) {
      f32x4 ae = MFMA(w1v[2 * kt],     zf, c1v[2 * kt]);
      f32x4 ao = MFMA(w1v[2 * kt + 1], zf, c1v[2 * kt + 1]);
      h1f[kt] = mk4(pk2(tanh_fast(ae[0]), tanh_fast(ae[1])),
                    pk2(tanh_fast(ae[2]), tanh_fast(ae[3])),
                    pk2(tanh_fast(ao[0]), tanh_fast(ao[1])),
                    pk2(tanh_fast(ao[2]), tanh_fast(ao[3])));
    }

    // ---- drift L2: h2 = tanh(h1 @ W2 + db2), two halves to cap live accs ----
    sh8 h2f[4];
    {
      f32x4 a2[4];
      #pragma unroll
      for (int t2 = 0; t2 < 4; ++t2) {
        f32x4 acc = *(const f32x4*)&lds.u.s.db2l[wave][t2 * 16 + quad * 4];
        #pragma unroll
        for (int kt = 0; kt < 4; ++kt) {
          sh8 wb = (t2 < 2) ? w2a[t2][kt]
                            : *(const sh8*)&lds.u.s.wfr[W2F + (t2 - 2) * 4 + kt][lane][0];
          acc = MFMA(wb, h1f[kt], acc);
        }
        a2[t2] = acc;
      }
      h2f[0] = mk4(pk2(tanh_fast(a2[0][0]), tanh_fast(a2[0][1])),
                   pk2(tanh_fast(a2[0][2]), tanh_fast(a2[0][3])),
                   pk2(tanh_fast(a2[1][0]), tanh_fast(a2[1][1])),
                   pk2(tanh_fast(a2[1][2]), tanh_fast(a2[1][3])));
      h2f[1] = mk4(pk2(tanh_fast(a2[2][0]), tanh_fast(a2[2][1])),
                   pk2(tanh_fast(a2[2][2]), tanh_fast(a2[2][3])),
                   pk2(tanh_fast(a2[3][0]), tanh_fast(a2[3][1])),
                   pk2(tanh_fast(a2[3][2]), tanh_fast(a2[3][3])));
    }
    {
      f32x4 a2[4];
      #pragma unroll
      for (int t2 = 0; t2 < 4; ++t2) {
        f32x4 acc = *(const f32x4*)&lds.u.s.db2l[wave][(t2 + 4) * 16 + quad * 4];
        #pragma unroll
        for (int kt = 0; kt < 4; ++kt) {
          sh8 wb = *(const sh8*)&lds.u.s.wfr[W2F + (t2 + 2) * 4 + kt][lane][0];
          acc = MFMA(wb, h1f[kt], acc);
        }
        a2[t2] = acc;
      }
      h2f[2] = mk4(pk2(tanh_fast(a2[0][0]), tanh_fast(a2[0][1])),
                   pk2(tanh_fast(a2[0][2]), tanh_fast(a2[0][3])),
                   pk2(tanh_fast(a2[1][0]), tanh_fast(a2[1][1])),
                   pk2(tanh_fast(a2[1][2]), tanh_fast(a2[1][3])));
      h2f[3] = mk4(pk2(tanh_fast(a2[2][0]), tanh_fast(a2[2][1])),
                   pk2(tanh_fast(a2[2][2]), tanh_fast(a2[2][3])),
                   pk2(tanh_fast(a2[3][0]), tanh_fast(a2[3][1])),
                   pk2(tanh_fast(a2[3][2]), tanh_fast(a2[3][3])));
    }

    // ---- drift L3 ----
    f32x4 accd = cd3v;
    #pragma unroll
    for (int kt = 0; kt < 4; ++kt) {
      sh8 w3v = *(const sh8*)&lds.u.s.wfr[W3F + kt][lane][0];
      accd = MFMA(w3v, h2f[kt], accd);
    }

    // ---- EM update + vector store ----
    {
      float f0 = accf[0] * sdt, f1 = accf[1] * sdt;
      float f2 = accf[2] * sdt, f3 = accf[3] * sdt;
      zreg[0] = __builtin_fmaf(f0, eps0, __builtin_fmaf(accd[0], dtv, zreg[0]));
      zreg[1] = __builtin_fmaf(f1, eps1, __builtin_fmaf(accd[1], dtv, zreg[1]));
      zreg[2] = __builtin_fmaf(f2, eps2, __builtin_fmaf(accd[2], dtv, zreg[2]));
      zreg[3] = __builtin_fmaf(f3, eps3, __builtin_fmaf(accd[3], dtv, zreg[3]));
    }
    if (quad < 2) {
      *(f32x2*)op       = (f32x2){zreg[0], zreg[1]};
      *(f32x2*)(op + 2) = (f32x2){zreg[2], zreg[3]};
    } else if (quad == 2) {
      *(f32x2*)op       = (f32x2){zreg[0], zreg[1]};
    }
    op += (size_t)B_TOT * 10;
    zreg[2] = (quad == 2) ? tnext : zreg[2];   // refresh t feature
    tcur = tnext;
  }
}

extern "C" void kernel_launch(void* const* d_in, const int* in_sizes, int n_in,
                              void* d_out, int out_size, void* d_ws, size_t ws_size,
                              hipStream_t stream) {
  (void)in_sizes; (void)n_in; (void)d_ws; (void)ws_size; (void)out_size;
  const float* z0       = (const float*)d_in[0];
  const float* activity = (const float*)d_in[1];
  const float* rest     = (const float*)d_in[2];
  const float* ts       = (const float*)d_in[3];
  const float* noise    = (const float*)d_in[4];
  const float* aW1 = (const float*)d_in[5];
  const float* ab1 = (const float*)d_in[6];
  const float* aW2 = (const float*)d_in[7];
  const float* ab2 = (const float*)d_in[8];
  const float* rW1 = (const float*)d_in[9];
  const float* rb1 = (const float*)d_in[10];
  const float* rW2 = (const float*)d_in[11];
  const float* rb2 = (const float*)d_in[12];
  const float* dW1 = (const float*)d_in[13];
  const float* db1 = (const float*)d_in[14];
  const float* dW2 = (const float*)d_in[15];
  const float* db2 = (const float*)d_in[16];
  const float* dW3 = (const float*)d_in[17];
  const float* db3 = (const float*)d_in[18];
  const float* gW1 = (const float*)d_in[19];
  const float* gb1 = (const float*)d_in[20];
  const float* gW2 = (const float*)d_in[21];
  const float* gb2 = (const float*)d_in[22];
  float* out = (float*)d_out;

  dim3 grid(B_TOT / MT), block(256);
  sde_kernel<<<grid, block, 0, stream>>>(
      z0, activity, rest, ts, noise,
      aW1, ab1, aW2, ab2, rW1, rb1, rW2, rb2,
      dW1, db1, dW2, db2, dW3, db3,
      gW1, gb1, gW2, gb2, out);
}

// Round 3
// 702.932 us; speedup vs baseline: 1.5421x; 1.5225x over previous
//
#include <hip/hip_runtime.h>
#include <cstdint>
#include <cstddef>

// LatentNeuralSDE: 100 sequential EM steps, B=32768, LAT=10.
// R6: R4/R5 transpose-free MFMA dataflow + anti-LICM memory clobber.
// R5 post-mortem: with no in-loop LDS writes, LICM hoisted every
// (loop-invariant-address) weight-fragment load out of the step loop,
// recreating the all-in-register structure -> ~240 live regs -> scratch
// spill, reloaded per step = 1.9 GB FETCH on the serial chain. Fix: an
// empty asm volatile memory clobber at the top of each step pins the
// fragment reads in-loop (short live ranges); all weight frags now live
// in frag-linear LDS (47 frags, conflict-free contiguous reads), only
// c1v/biases/z stay in registers. No in-loop barriers (all LDS traffic
// wave-private or read-only).

#define B_TOT 32768
#define NSTEP 100
#define MT    64

typedef __attribute__((ext_vector_type(8))) short sh8;
typedef __attribute__((ext_vector_type(4))) float f32x4;
typedef __attribute__((ext_vector_type(2))) float f32x2;
typedef __attribute__((ext_vector_type(4))) unsigned int u32x4;

#define MFMA(a, b, c) __builtin_amdgcn_mfma_f32_16x16x32_bf16((a), (b), (c), 0, 0, 0)

// fragment table layout in LDS
#define W1F 0            // 8 frags  (L1 z-part, t=0..7)
#define G1F 8            // 2 frags
#define G2F 10           // 1 frag
#define W2F 11           // 32 frags: W2F + t2*4 + kt
#define W3F 43           // 4 frags
#define NFR 47

struct __align__(16) Lds {
  union {
    float ar[MT][100];               // encoder outputs (prologue only)
    struct {
      short wfr[NFR][64][8];         // frag-linear weight frags (conflict-free)
      float db2l[4][128];            // per-wave db2 copy (broadcast reads)
    } s;
  } u;                               // 50176 B
  float tsl[104];
};

static __device__ __forceinline__ short f2bf(float v) {  // RTNE (weights, one-time)
  unsigned u = __builtin_bit_cast(unsigned, v);
  u += 0x7fffu + ((u >> 16) & 1u);
  return (short)(u >> 16);
}
// pack two floats -> (bf16(hi)<<16)|bf16(lo) : 2 adds + 1 v_perm
static __device__ __forceinline__ unsigned pk2(float lo, float hi) {
  unsigned a = __builtin_bit_cast(unsigned, lo) + 0x8000u;
  unsigned b = __builtin_bit_cast(unsigned, hi) + 0x8000u;
  return __builtin_amdgcn_perm(b, a, 0x07060302u);
}
static __device__ __forceinline__ sh8 mk4(unsigned a, unsigned b, unsigned c, unsigned d) {
  return __builtin_bit_cast(sh8, (u32x4){a, b, c, d});
}
static __device__ __forceinline__ float tanh_fast(float x) {
  float e = __builtin_amdgcn_exp2f(x * 2.8853900817779268f);
  float r = __builtin_amdgcn_rcpf(e + 1.0f);
  return __builtin_fmaf(-2.0f, r, 1.0f);
}
static __device__ __forceinline__ float softplus_fast(float x) {
  float e = __builtin_amdgcn_exp2f(x * 1.4426950408889634f);
  float l = __builtin_amdgcn_logf(e + 1.0f) * 0.6931471805599453f;
  return (x > 20.0f) ? x : l;
}

__global__ __launch_bounds__(256, 2)
void sde_kernel(const float* __restrict__ z0, const float* __restrict__ activity,
                const float* __restrict__ rest, const float* __restrict__ ts,
                const float* __restrict__ noise,
                const float* __restrict__ aW1, const float* __restrict__ ab1,
                const float* __restrict__ aW2, const float* __restrict__ ab2,
                const float* __restrict__ rW1, const float* __restrict__ rb1,
                const float* __restrict__ rW2, const float* __restrict__ rb2,
                const float* __restrict__ dW1, const float* __restrict__ db1,
                const float* __restrict__ dW2, const float* __restrict__ db2,
                const float* __restrict__ dW3, const float* __restrict__ db3,
                const float* __restrict__ gW1, const float* __restrict__ gb1,
                const float* __restrict__ gW2, const float* __restrict__ gb2,
                float* __restrict__ out)
{
  __shared__ Lds lds;
  const int tid  = threadIdx.x;
  const int lane = tid & 63;
  const int wave = tid >> 6;
  const int n    = lane & 15;   // batch col (B/D col) / A-row m in weight gathers
  const int quad = lane >> 4;
  const int slab = wave * 16;
  const int mblk = blockIdx.x * MT;
  const int rowg = mblk + slab + n;   // this lane's global batch row

  if (tid < 101) lds.tsl[tid] = ts[tid];
  float tcur = ts[0];

  // ---------------- encoders -> ar (wave-private rows) ----------------
  {
    const int e = tid >> 2, p = tid & 3;
    const int eg = mblk + e;
    float act[6], rst[3];
    #pragma unroll
    for (int i = 0; i < 6; ++i) act[i] = activity[eg * 6 + i];
    #pragma unroll
    for (int i = 0; i < 3; ++i) rst[i] = rest[eg * 3 + i];
    float ha[32];
    for (int j = 0; j < 32; ++j) {
      float s = ab1[j];
      #pragma unroll
      for (int i = 0; i < 6; ++i) s = __builtin_fmaf(act[i], aW1[i * 32 + j], s);
      ha[j] = fmaxf(s, 0.0f);
    }
    float hr[16];
    for (int j = 0; j < 16; ++j) {
      float s = rb1[j];
      #pragma unroll
      for (int i = 0; i < 3; ++i) s = __builtin_fmaf(rst[i], rW1[i * 16 + j], s);
      hr[j] = fmaxf(s, 0.0f);
    }
    for (int oo = 0; oo < 24; ++oo) {
      int o = p * 24 + oo;
      float v;
      if (o < 64) {
        v = ab2[o];
        for (int j = 0; j < 32; ++j) v = __builtin_fmaf(ha[j], aW2[j * 64 + o], v);
      } else {
        int ro = o - 64;
        v = rb2[ro];
        for (int j = 0; j < 16; ++j) v = __builtin_fmaf(hr[j], rW2[j * 32 + ro], v);
      }
      lds.u.ar[e][o] = v;
    }
  }
  // no barrier needed: each wave reads only its own 16 ar rows below.

  // ---------------- c1 context fold: c1[batch n][feat 16t+4q+r] ----------------
  f32x4 c1v[8];
  #pragma unroll
  for (int t = 0; t < 8; ++t)
    c1v[t] = *(const f32x4*)(db1 + t * 16 + quad * 4);
  for (int k = 0; k < 96; ++k) {
    float av = lds.u.ar[slab + n][k];
    #pragma unroll
    for (int t = 0; t < 8; ++t) {
      f32x4 w = *(const f32x4*)(dW1 + (10 + k) * 128 + t * 16 + quad * 4);
      #pragma unroll
      for (int r = 0; r < 4; ++r) c1v[t][r] = __builtin_fmaf(av, w[r], c1v[t][r]);
    }
  }
  __syncthreads();   // ar dead everywhere; wfr/db2l (union) may now be written.

  // ---------------- weight A-frags (W^T, pi-permuted k) -> LDS ----------------
  // pi: slot (quad,j) -> feature fbase + 16*(j>>2) + 4*quad + (j&3)
  // All waves write identical per-lane data; duplicate writes are benign and
  // each wave's own writes are visible to it in-order (no barrier needed).
  #pragma unroll
  for (int t = 0; t < 8; ++t) {            // L1 z-part: K=16 real (j>=4 zero)
    short tmp[8];
    #pragma unroll
    for (int j = 0; j < 8; ++j) {
      float v = 0.0f;
      if (j < 4) {
        int f = 4 * quad + j;
        if (f < 10) v = dW1[f * 128 + t * 16 + n];
        else if (f == 10) v = dW1[106 * 128 + t * 16 + n];
      }
      tmp[j] = f2bf(v);
    }
    *(sh8*)&lds.u.s.wfr[W1F + t][lane][0] =
        (sh8){tmp[0],tmp[1],tmp[2],tmp[3],tmp[4],tmp[5],tmp[6],tmp[7]};
  }
  #pragma unroll
  for (int t2 = 0; t2 < 8; ++t2) {         // W2^T, all 32 frags -> LDS
    #pragma unroll
    for (int kt = 0; kt < 4; ++kt) {
      short tmp[8];
      #pragma unroll
      for (int j = 0; j < 8; ++j) {
        int f = 32 * kt + 16 * (j >> 2) + 4 * quad + (j & 3);
        tmp[j] = f2bf(dW2[f * 128 + t2 * 16 + n]);
      }
      *(sh8*)&lds.u.s.wfr[W2F + t2 * 4 + kt][lane][0] =
          (sh8){tmp[0],tmp[1],tmp[2],tmp[3],tmp[4],tmp[5],tmp[6],tmp[7]};
    }
  }
  #pragma unroll
  for (int kt = 0; kt < 4; ++kt) {         // W3^T: rows m>=10 zeroed
    short tmp[8];
    #pragma unroll
    for (int j = 0; j < 8; ++j) {
      int f = 32 * kt + 16 * (j >> 2) + 4 * quad + (j & 3);
      tmp[j] = f2bf((n < 10) ? dW3[f * 10 + n] : 0.0f);
    }
    *(sh8*)&lds.u.s.wfr[W3F + kt][lane][0] =
        (sh8){tmp[0],tmp[1],tmp[2],tmp[3],tmp[4],tmp[5],tmp[6],tmp[7]};
  }
  #pragma unroll
  for (int t = 0; t < 2; ++t) {            // G1^T: K=16 real
    short tmp[8];
    #pragma unroll
    for (int j = 0; j < 8; ++j) {
      float v = 0.0f;
      if (j < 4) {
        int f = 4 * quad + j;
        if (f < 10) v = gW1[f * 32 + t * 16 + n];
        else if (f == 10) v = gW1[10 * 32 + t * 16 + n];
      }
      tmp[j] = f2bf(v);
    }
    *(sh8*)&lds.u.s.wfr[G1F + t][lane][0] =
        (sh8){tmp[0],tmp[1],tmp[2],tmp[3],tmp[4],tmp[5],tmp[6],tmp[7]};
  }
  {                                        // G2^T: K=32 (both halves real)
    short tmp[8];
    #pragma unroll
    for (int j = 0; j < 8; ++j) {
      int h = 16 * (j >> 2) + 4 * quad + (j & 3);
      tmp[j] = f2bf((n < 10) ? gW2[h * 10 + n] : 0.0f);
    }
    *(sh8*)&lds.u.s.wfr[G2F][lane][0] =
        (sh8){tmp[0],tmp[1],tmp[2],tmp[3],tmp[4],tmp[5],tmp[6],tmp[7]};
  }
  // per-wave db2 copy (wave-private; broadcast-read in loop)
  lds.u.s.db2l[wave][lane]      = db2[lane];
  lds.u.s.db2l[wave][lane + 64] = db2[lane + 64];

  // ---------------- biases in D layout (row = 4q + r) ----------------
  f32x4 cd3v, cg1v0, cg1v1, cg2v;
  #pragma unroll
  for (int r = 0; r < 4; ++r) {
    int o = quad * 4 + r;
    cd3v[r]  = (o < 10) ? db3[o] : 0.0f;
    cg1v0[r] = gb1[o];
    cg1v1[r] = gb1[16 + o];
    cg2v[r]  = (o < 10) ? gb2[o] : 0.0f;
  }

  // ---------------- z init (registers, D layout), out[0] ----------------
  float zreg[4] = {0.0f, 0.0f, 0.0f, 0.0f};
  {
    const float* zp = z0 + (size_t)rowg * 10 + quad * 4;
    float* o0 = out + (size_t)rowg * 10 + quad * 4;
    if (quad < 2) {
      f32x2 a = *(const f32x2*)zp, b = *(const f32x2*)(zp + 2);
      zreg[0] = a.x; zreg[1] = a.y; zreg[2] = b.x; zreg[3] = b.y;
      *(f32x2*)o0 = a; *(f32x2*)(o0 + 2) = b;
    } else if (quad == 2) {
      f32x2 a = *(const f32x2*)zp;
      zreg[0] = a.x; zreg[1] = a.y;
      *(f32x2*)o0 = a;
      zreg[2] = tcur;               // feature 10 = t; feature 11 stays 0
    }
  }
  const float* np = noise + (size_t)rowg * 10 + quad * 4;
  float*       op = out + (size_t)B_TOT * 10 + (size_t)rowg * 10 + quad * 4;

  #pragma unroll 1
  for (int s = 0; s < NSTEP; ++s) {
    // Anti-LICM: compiler must assume LDS changed -> frag reads stay
    // in-loop with short live ranges (R5's hoist->spill killer). Free.
    asm volatile("" ::: "memory");

    float tnext = lds.tsl[s + 1];
    float dtv   = tnext - tcur;
    float sdt   = __builtin_amdgcn_sqrtf(dtv);

    // noise prefetch (vector, used at step end)
    float eps0 = 0.0f, eps1 = 0.0f, eps2 = 0.0f, eps3 = 0.0f;
    if (quad < 2) {
      f32x2 a = *(const f32x2*)np, b = *(const f32x2*)(np + 2);
      eps0 = a.x; eps1 = a.y; eps2 = b.x; eps3 = b.y;
    } else if (quad == 2) {
      f32x2 a = *(const f32x2*)np;
      eps0 = a.x; eps1 = a.y;
    }
    np += (size_t)B_TOT * 10;

    // z B-frag (k = 4q + r via pi; upper half zero-weighted)
    sh8 zf = mk4(pk2(zreg[0], zreg[1]), pk2(zreg[2], zreg[3]), 0u, 0u);

    // ---- diffusion: hg = softplus(zt @ G1), accf = hg @ G2 ----
    f32x4 accf;
    {
      sh8 g1v0 = *(const sh8*)&lds.u.s.wfr[G1F + 0][lane][0];
      sh8 g1v1 = *(const sh8*)&lds.u.s.wfr[G1F + 1][lane][0];
      f32x4 g0 = MFMA(g1v0, zf, cg1v0);
      f32x4 g1 = MFMA(g1v1, zf, cg1v1);
      sh8 gb = mk4(pk2(softplus_fast(g0[0]), softplus_fast(g0[1])),
                   pk2(softplus_fast(g0[2]), softplus_fast(g0[3])),
                   pk2(softplus_fast(g1[0]), softplus_fast(g1[1])),
                   pk2(softplus_fast(g1[2]), softplus_fast(g1[3])));
      sh8 g2v = *(const sh8*)&lds.u.s.wfr[G2F][lane][0];
      accf = MFMA(g2v, gb, cg2v);
    }

    // ---- drift L1: h1 = tanh(zt @ W1z + c1) -> B-frags in regs ----
    sh8 h1f[4];
    #pragma unroll
    for (int kt = 0; kt < 4; ++kt) {
      sh8 w1e = *(const sh8*)&lds.u.s.wfr[W1F + 2 * kt][lane][0];
      sh8 w1o = *(const sh8*)&lds.u.s.wfr[W1F + 2 * kt + 1][lane][0];
      f32x4 ae = MFMA(w1e, zf, c1v[2 * kt]);
      f32x4 ao = MFMA(w1o, zf, c1v[2 * kt + 1]);
      h1f[kt] = mk4(pk2(tanh_fast(ae[0]), tanh_fast(ae[1])),
                    pk2(tanh_fast(ae[2]), tanh_fast(ae[3])),
                    pk2(tanh_fast(ao[0]), tanh_fast(ao[1])),
                    pk2(tanh_fast(ao[2]), tanh_fast(ao[3])));
    }

    // ---- drift L2: h2 = tanh(h1 @ W2 + db2), two halves to cap live accs ----
    sh8 h2f[4];
    {
      f32x4 a2[4];
      #pragma unroll
      for (int t2 = 0; t2 < 4; ++t2) {
        f32x4 acc = *(const f32x4*)&lds.u.s.db2l[wave][t2 * 16 + quad * 4];
        #pragma unroll
        for (int kt = 0; kt < 4; ++kt) {
          sh8 wb = *(const sh8*)&lds.u.s.wfr[W2F + t2 * 4 + kt][lane][0];
          acc = MFMA(wb, h1f[kt], acc);
        }
        a2[t2] = acc;
      }
      h2f[0] = mk4(pk2(tanh_fast(a2[0][0]), tanh_fast(a2[0][1])),
                   pk2(tanh_fast(a2[0][2]), tanh_fast(a2[0][3])),
                   pk2(tanh_fast(a2[1][0]), tanh_fast(a2[1][1])),
                   pk2(tanh_fast(a2[1][2]), tanh_fast(a2[1][3])));
      h2f[1] = mk4(pk2(tanh_fast(a2[2][0]), tanh_fast(a2[2][1])),
                   pk2(tanh_fast(a2[2][2]), tanh_fast(a2[2][3])),
                   pk2(tanh_fast(a2[3][0]), tanh_fast(a2[3][1])),
                   pk2(tanh_fast(a2[3][2]), tanh_fast(a2[3][3])));
    }
    {
      f32x4 a2[4];
      #pragma unroll
      for (int t2 = 0; t2 < 4; ++t2) {
        f32x4 acc = *(const f32x4*)&lds.u.s.db2l[wave][(t2 + 4) * 16 + quad * 4];
        #pragma unroll
        for (int kt = 0; kt < 4; ++kt) {
          sh8 wb = *(const sh8*)&lds.u.s.wfr[W2F + (t2 + 4) * 4 + kt][lane][0];
          acc = MFMA(wb, h1f[kt], acc);
        }
        a2[t2] = acc;
      }
      h2f[2] = mk4(pk2(tanh_fast(a2[0][0]), tanh_fast(a2[0][1])),
                   pk2(tanh_fast(a2[0][2]), tanh_fast(a2[0][3])),
                   pk2(tanh_fast(a2[1][0]), tanh_fast(a2[1][1])),
                   pk2(tanh_fast(a2[1][2]), tanh_fast(a2[1][3])));
      h2f[3] = mk4(pk2(tanh_fast(a2[2][0]), tanh_fast(a2[2][1])),
                   pk2(tanh_fast(a2[2][2]), tanh_fast(a2[2][3])),
                   pk2(tanh_fast(a2[3][0]), tanh_fast(a2[3][1])),
                   pk2(tanh_fast(a2[3][2]), tanh_fast(a2[3][3])));
    }

    // ---- drift L3 ----
    f32x4 accd = cd3v;
    #pragma unroll
    for (int kt = 0; kt < 4; ++kt) {
      sh8 w3v = *(const sh8*)&lds.u.s.wfr[W3F + kt][lane][0];
      accd = MFMA(w3v, h2f[kt], accd);
    }

    // ---- EM update + vector store ----
    {
      float f0 = accf[0] * sdt, f1 = accf[1] * sdt;
      float f2 = accf[2] * sdt, f3 = accf[3] * sdt;
      zreg[0] = __builtin_fmaf(f0, eps0, __builtin_fmaf(accd[0], dtv, zreg[0]));
      zreg[1] = __builtin_fmaf(f1, eps1, __builtin_fmaf(accd[1], dtv, zreg[1]));
      zreg[2] = __builtin_fmaf(f2, eps2, __builtin_fmaf(accd[2], dtv, zreg[2]));
      zreg[3] = __builtin_fmaf(f3, eps3, __builtin_fmaf(accd[3], dtv, zreg[3]));
    }
    if (quad < 2) {
      *(f32x2*)op       = (f32x2){zreg[0], zreg[1]};
      *(f32x2*)(op + 2) = (f32x2){zreg[2], zreg[3]};
    } else if (quad == 2) {
      *(f32x2*)op       = (f32x2){zreg[0], zreg[1]};
    }
    op += (size_t)B_TOT * 10;
    zreg[2] = (quad == 2) ? tnext : zreg[2];   // refresh t feature
    tcur = tnext;
  }
}

extern "C" void kernel_launch(void* const* d_in, const int* in_sizes, int n_in,
                              void* d_out, int out_size, void* d_ws, size_t ws_size,
                              hipStream_t stream) {
  (void)in_sizes; (void)n_in; (void)d_ws; (void)ws_size; (void)out_size;
  const float* z0       = (const float*)d_in[0];
  const float* activity = (const float*)d_in[1];
  const float* rest     = (const float*)d_in[2];
  const float* ts       = (const float*)d_in[3];
  const float* noise    = (const float*)d_in[4];
  const float* aW1 = (const float*)d_in[5];
  const float* ab1 = (const float*)d_in[6];
  const float* aW2 = (const float*)d_in[7];
  const float* ab2 = (const float*)d_in[8];
  const float* rW1 = (const float*)d_in[9];
  const float* rb1 = (const float*)d_in[10];
  const float* rW2 = (const float*)d_in[11];
  const float* rb2 = (const float*)d_in[12];
  const float* dW1 = (const float*)d_in[13];
  const float* db1 = (const float*)d_in[14];
  const float* dW2 = (const float*)d_in[15];
  const float* db2 = (const float*)d_in[16];
  const float* dW3 = (const float*)d_in[17];
  const float* db3 = (const float*)d_in[18];
  const float* gW1 = (const float*)d_in[19];
  const float* gb1 = (const float*)d_in[20];
  const float* gW2 = (const float*)d_in[21];
  const float* gb2 = (const float*)d_in[22];
  float* out = (float*)d_out;

  dim3 grid(B_TOT / MT), block(256);
  sde_kernel<<<grid, block, 0, stream>>>(
      z0, activity, rest, ts, noise,
      aW1, ab1, aW2, ab2, rW1, rb1, rW2, rb2,
      dW1, db1, dW2, db2, dW3, db3,
      gW1, gb1, gW2, gb2, out);
}

// Round 4
// 579.326 us; speedup vs baseline: 1.8711x; 1.2134x over previous
//
#include <hip/hip_runtime.h>
#include <cstdint>
#include <cstddef>

// LatentNeuralSDE: 100 sequential EM steps, B=32768, LAT=10.
// R7: R6 dataflow + step-tail weights in persistent registers.
// R6 post-mortem: latency-bound at 2 waves/SIMD; 55 LDS frag reads/wave-step
// put a ~220us LDS-issue floor and repeated ~120cyc ds latencies on the
// serial chain. R7 register set: W2 t2=0..3 (16 frags), W3 (4), G1/G2 (3)
// persistent in VGPRs (budget 256 at 2 waves/SIMD; est peak ~215); db2
// folded into tanh_b bias (kb2, R3-proven) deleting its LDS reads. W1 +
// W2 t2=4..7 stay in frag-linear LDS behind the anti-LICM clobber; W1's
// latency hides under the register-resident diffusion branch. LDS ops
// 55 -> 24 per wave-step; L2a/L3/G are pure-register MFMA chains.

#define B_TOT 32768
#define NSTEP 100
#define MT    64

typedef __attribute__((ext_vector_type(8))) short sh8;
typedef __attribute__((ext_vector_type(4))) float f32x4;
typedef __attribute__((ext_vector_type(2))) float f32x2;
typedef __attribute__((ext_vector_type(4))) unsigned int u32x4;

#define MFMA(a, b, c) __builtin_amdgcn_mfma_f32_16x16x32_bf16((a), (b), (c), 0, 0, 0)

// fragment table layout in LDS
#define W1F 0            // 8 frags  (L1 z-part, t=0..7)
#define W2F 8            // 16 frags (t2=4..7): W2F + (t2-4)*4 + kt
#define NFR 24

struct __align__(16) Lds {
  union {
    float ar[MT][100];               // encoder outputs (prologue only)
    struct {
      short wfr[NFR][64][8];         // frag-linear weight frags (conflict-free)
    } s;
  } u;                               // 25600 B
  float tsl[104];
};

static __device__ __forceinline__ short f2bf(float v) {  // RTNE (weights, one-time)
  unsigned u = __builtin_bit_cast(unsigned, v);
  u += 0x7fffu + ((u >> 16) & 1u);
  return (short)(u >> 16);
}
// pack two floats -> (bf16(hi)<<16)|bf16(lo) : 2 adds + 1 v_perm
static __device__ __forceinline__ unsigned pk2(float lo, float hi) {
  unsigned a = __builtin_bit_cast(unsigned, lo) + 0x8000u;
  unsigned b = __builtin_bit_cast(unsigned, hi) + 0x8000u;
  return __builtin_amdgcn_perm(b, a, 0x07060302u);
}
static __device__ __forceinline__ sh8 mk4(unsigned a, unsigned b, unsigned c, unsigned d) {
  return __builtin_bit_cast(sh8, (u32x4){a, b, c, d});
}
static __device__ __forceinline__ float tanh_fast(float x) {
  float e = __builtin_amdgcn_exp2f(x * 2.8853900817779268f);
  float r = __builtin_amdgcn_rcpf(e + 1.0f);
  return __builtin_fmaf(-2.0f, r, 1.0f);
}
static __device__ __forceinline__ float tanh_b(float x, float kb) {  // tanh(x+b)
  float e = __builtin_amdgcn_exp2f(__builtin_fmaf(x, 2.8853900817779268f, kb));
  float r = __builtin_amdgcn_rcpf(e + 1.0f);
  return __builtin_fmaf(-2.0f, r, 1.0f);
}
static __device__ __forceinline__ float softplus_fast(float x) {
  float e = __builtin_amdgcn_exp2f(x * 1.4426950408889634f);
  float l = __builtin_amdgcn_logf(e + 1.0f) * 0.6931471805599453f;
  return (x > 20.0f) ? x : l;
}

__global__ __launch_bounds__(256, 2)
void sde_kernel(const float* __restrict__ z0, const float* __restrict__ activity,
                const float* __restrict__ rest, const float* __restrict__ ts,
                const float* __restrict__ noise,
                const float* __restrict__ aW1, const float* __restrict__ ab1,
                const float* __restrict__ aW2, const float* __restrict__ ab2,
                const float* __restrict__ rW1, const float* __restrict__ rb1,
                const float* __restrict__ rW2, const float* __restrict__ rb2,
                const float* __restrict__ dW1, const float* __restrict__ db1,
                const float* __restrict__ dW2, const float* __restrict__ db2,
                const float* __restrict__ dW3, const float* __restrict__ db3,
                const float* __restrict__ gW1, const float* __restrict__ gb1,
                const float* __restrict__ gW2, const float* __restrict__ gb2,
                float* __restrict__ out)
{
  __shared__ Lds lds;
  const int tid  = threadIdx.x;
  const int lane = tid & 63;
  const int wave = tid >> 6;
  const int n    = lane & 15;   // batch col (B/D col) / A-row m in weight gathers
  const int quad = lane >> 4;
  const int slab = wave * 16;
  const int mblk = blockIdx.x * MT;
  const int rowg = mblk + slab + n;   // this lane's global batch row

  if (tid < 101) lds.tsl[tid] = ts[tid];
  float tcur = ts[0];

  // ---------------- encoders -> ar (wave-private rows) ----------------
  {
    const int e = tid >> 2, p = tid & 3;
    const int eg = mblk + e;
    float act[6], rst[3];
    #pragma unroll
    for (int i = 0; i < 6; ++i) act[i] = activity[eg * 6 + i];
    #pragma unroll
    for (int i = 0; i < 3; ++i) rst[i] = rest[eg * 3 + i];
    float ha[32];
    for (int j = 0; j < 32; ++j) {
      float s = ab1[j];
      #pragma unroll
      for (int i = 0; i < 6; ++i) s = __builtin_fmaf(act[i], aW1[i * 32 + j], s);
      ha[j] = fmaxf(s, 0.0f);
    }
    float hr[16];
    for (int j = 0; j < 16; ++j) {
      float s = rb1[j];
      #pragma unroll
      for (int i = 0; i < 3; ++i) s = __builtin_fmaf(rst[i], rW1[i * 16 + j], s);
      hr[j] = fmaxf(s, 0.0f);
    }
    for (int oo = 0; oo < 24; ++oo) {
      int o = p * 24 + oo;
      float v;
      if (o < 64) {
        v = ab2[o];
        for (int j = 0; j < 32; ++j) v = __builtin_fmaf(ha[j], aW2[j * 64 + o], v);
      } else {
        int ro = o - 64;
        v = rb2[ro];
        for (int j = 0; j < 16; ++j) v = __builtin_fmaf(hr[j], rW2[j * 32 + ro], v);
      }
      lds.u.ar[e][o] = v;
    }
  }
  // no barrier needed: each wave reads only its own 16 ar rows below.

  // ---------------- c1 context fold: c1[batch n][feat 16t+4q+r] ----------------
  f32x4 c1v[8];
  #pragma unroll
  for (int t = 0; t < 8; ++t)
    c1v[t] = *(const f32x4*)(db1 + t * 16 + quad * 4);
  for (int k = 0; k < 96; ++k) {
    float av = lds.u.ar[slab + n][k];
    #pragma unroll
    for (int t = 0; t < 8; ++t) {
      f32x4 w = *(const f32x4*)(dW1 + (10 + k) * 128 + t * 16 + quad * 4);
      #pragma unroll
      for (int r = 0; r < 4; ++r) c1v[t][r] = __builtin_fmaf(av, w[r], c1v[t][r]);
    }
  }
  __syncthreads();   // ar dead everywhere; wfr (union) may now be written.

  // ---------------- weight A-frags (W^T, pi-permuted k) ----------------
  // pi: slot (quad,j) -> feature fbase + 16*(j>>2) + 4*quad + (j&3)
  // LDS frags: all waves write identical data; each wave's own writes are
  // visible to it in-order (no barrier needed).
  #pragma unroll
  for (int t = 0; t < 8; ++t) {            // L1 z-part -> LDS (K=16 real)
    short tmp[8];
    #pragma unroll
    for (int j = 0; j < 8; ++j) {
      float v = 0.0f;
      if (j < 4) {
        int f = 4 * quad + j;
        if (f < 10) v = dW1[f * 128 + t * 16 + n];
        else if (f == 10) v = dW1[106 * 128 + t * 16 + n];
      }
      tmp[j] = f2bf(v);
    }
    *(sh8*)&lds.u.s.wfr[W1F + t][lane][0] =
        (sh8){tmp[0],tmp[1],tmp[2],tmp[3],tmp[4],tmp[5],tmp[6],tmp[7]};
  }
  sh8 w2a[4][4];                           // W2^T t2=0..3 regs, t2=4..7 LDS
  #pragma unroll
  for (int t2 = 0; t2 < 8; ++t2) {
    #pragma unroll
    for (int kt = 0; kt < 4; ++kt) {
      short tmp[8];
      #pragma unroll
      for (int j = 0; j < 8; ++j) {
        int f = 32 * kt + 16 * (j >> 2) + 4 * quad + (j & 3);
        tmp[j] = f2bf(dW2[f * 128 + t2 * 16 + n]);
      }
      sh8 fr = (sh8){tmp[0],tmp[1],tmp[2],tmp[3],tmp[4],tmp[5],tmp[6],tmp[7]};
      if (t2 < 4) w2a[t2][kt] = fr;
      else *(sh8*)&lds.u.s.wfr[W2F + (t2 - 4) * 4 + kt][lane][0] = fr;
    }
  }
  sh8 w3a[4];                              // W3^T regs: rows m>=10 zeroed
  #pragma unroll
  for (int kt = 0; kt < 4; ++kt) {
    short tmp[8];
    #pragma unroll
    for (int j = 0; j < 8; ++j) {
      int f = 32 * kt + 16 * (j >> 2) + 4 * quad + (j & 3);
      tmp[j] = f2bf((n < 10) ? dW3[f * 10 + n] : 0.0f);
    }
    w3a[kt] = (sh8){tmp[0],tmp[1],tmp[2],tmp[3],tmp[4],tmp[5],tmp[6],tmp[7]};
  }
  sh8 g1a[2];                              // G1^T regs: K=16 real
  #pragma unroll
  for (int t = 0; t < 2; ++t) {
    short tmp[8];
    #pragma unroll
    for (int j = 0; j < 8; ++j) {
      float v = 0.0f;
      if (j < 4) {
        int f = 4 * quad + j;
        if (f < 10) v = gW1[f * 32 + t * 16 + n];
        else if (f == 10) v = gW1[10 * 32 + t * 16 + n];
      }
      tmp[j] = f2bf(v);
    }
    g1a[t] = (sh8){tmp[0],tmp[1],tmp[2],tmp[3],tmp[4],tmp[5],tmp[6],tmp[7]};
  }
  sh8 g2a;                                 // G2^T reg: K=32 (both halves real)
  {
    short tmp[8];
    #pragma unroll
    for (int j = 0; j < 8; ++j) {
      int h = 16 * (j >> 2) + 4 * quad + (j & 3);
      tmp[j] = f2bf((n < 10) ? gW2[h * 10 + n] : 0.0f);
    }
    g2a = (sh8){tmp[0],tmp[1],tmp[2],tmp[3],tmp[4],tmp[5],tmp[6],tmp[7]};
  }

  // ---------------- bias folds ----------------
  float kb2[8];                            // db2 folded into tanh_b
  #pragma unroll
  for (int t = 0; t < 8; ++t) kb2[t] = db2[t * 16 + n] * 2.8853900817779268f;
  f32x4 cd3v, cg1v0, cg1v1, cg2v;
  #pragma unroll
  for (int r = 0; r < 4; ++r) {
    int o = quad * 4 + r;
    cd3v[r]  = (o < 10) ? db3[o] : 0.0f;
    cg1v0[r] = gb1[o];
    cg1v1[r] = gb1[16 + o];
    cg2v[r]  = (o < 10) ? gb2[o] : 0.0f;
  }
  const f32x4 zc = {0.0f, 0.0f, 0.0f, 0.0f};

  // ---------------- z init (registers, D layout), out[0] ----------------
  float zreg[4] = {0.0f, 0.0f, 0.0f, 0.0f};
  {
    const float* zp = z0 + (size_t)rowg * 10 + quad * 4;
    float* o0 = out + (size_t)rowg * 10 + quad * 4;
    if (quad < 2) {
      f32x2 a = *(const f32x2*)zp, b = *(const f32x2*)(zp + 2);
      zreg[0] = a.x; zreg[1] = a.y; zreg[2] = b.x; zreg[3] = b.y;
      *(f32x2*)o0 = a; *(f32x2*)(o0 + 2) = b;
    } else if (quad == 2) {
      f32x2 a = *(const f32x2*)zp;
      zreg[0] = a.x; zreg[1] = a.y;
      *(f32x2*)o0 = a;
      zreg[2] = tcur;               // feature 10 = t; feature 11 stays 0
    }
  }
  const float* np = noise + (size_t)rowg * 10 + quad * 4;
  float*       op = out + (size_t)B_TOT * 10 + (size_t)rowg * 10 + quad * 4;

  #pragma unroll 1
  for (int s = 0; s < NSTEP; ++s) {
    // Anti-LICM: keep the remaining LDS frag reads in-loop (R5 lesson).
    asm volatile("" ::: "memory");

    float tnext = lds.tsl[s + 1];
    float dtv   = tnext - tcur;
    float sdt   = __builtin_amdgcn_sqrtf(dtv);

    // noise prefetch (vector, used at step end)
    float eps0 = 0.0f, eps1 = 0.0f, eps2 = 0.0f, eps3 = 0.0f;
    if (quad < 2) {
      f32x2 a = *(const f32x2*)np, b = *(const f32x2*)(np + 2);
      eps0 = a.x; eps1 = a.y; eps2 = b.x; eps3 = b.y;
    } else if (quad == 2) {
      f32x2 a = *(const f32x2*)np;
      eps0 = a.x; eps1 = a.y;
    }
    np += (size_t)B_TOT * 10;

    // W1 frag reads issued early; latency hides under diffusion (reg frags)
    sh8 w1v[8];
    #pragma unroll
    for (int t = 0; t < 8; ++t)
      w1v[t] = *(const sh8*)&lds.u.s.wfr[W1F + t][lane][0];

    // z B-frag (k = 4q + r via pi; upper half zero-weighted)
    sh8 zf = mk4(pk2(zreg[0], zreg[1]), pk2(zreg[2], zreg[3]), 0u, 0u);

    // ---- diffusion: hg = softplus(zt @ G1), accf = hg @ G2 (all-register) ----
    f32x4 accf;
    {
      f32x4 g0 = MFMA(g1a[0], zf, cg1v0);
      f32x4 g1 = MFMA(g1a[1], zf, cg1v1);
      sh8 gb = mk4(pk2(softplus_fast(g0[0]), softplus_fast(g0[1])),
                   pk2(softplus_fast(g0[2]), softplus_fast(g0[3])),
                   pk2(softplus_fast(g1[0]), softplus_fast(g1[1])),
                   pk2(softplus_fast(g1[2]), softplus_fast(g1[3])));
      accf = MFMA(g2a, gb, cg2v);
    }

    // ---- drift L1: h1 = tanh(zt @ W1z + c1) -> B-frags in regs ----
    sh8 h1f[4];
    #pragma unroll
    for (int kt = 0; kt < 4; ++kt) {
      f32x4 ae = MFMA(w1v[2 * kt],     zf, c1v[2 * kt]);
      f32x4 ao = MFMA(w1v[2 * kt + 1], zf, c1v[2 * kt + 1]);
      h1f[kt] = mk4(pk2(tanh_fast(ae[0]), tanh_fast(ae[1])),
                    pk2(tanh_fast(ae[2]), tanh_fast(ae[3])),
                    pk2(tanh_fast(ao[0]), tanh_fast(ao[1])),
                    pk2(tanh_fast(ao[2]), tanh_fast(ao[3])));
    }

    // ---- drift L2: h2 = tanh(h1 @ W2 + db2); db2 folded into tanh_b ----
    sh8 h2f[4];
    {                                      // first half: W2 in registers
      f32x4 a2[4];
      #pragma unroll
      for (int t2 = 0; t2 < 4; ++t2) {
        f32x4 acc = zc;
        #pragma unroll
        for (int kt = 0; kt < 4; ++kt)
          acc = MFMA(w2a[t2][kt], h1f[kt], acc);
        a2[t2] = acc;
      }
      h2f[0] = mk4(pk2(tanh_b(a2[0][0], kb2[0]), tanh_b(a2[0][1], kb2[0])),
                   pk2(tanh_b(a2[0][2], kb2[0]), tanh_b(a2[0][3], kb2[0])),
                   pk2(tanh_b(a2[1][0], kb2[1]), tanh_b(a2[1][1], kb2[1])),
                   pk2(tanh_b(a2[1][2], kb2[1]), tanh_b(a2[1][3], kb2[1])));
      h2f[1] = mk4(pk2(tanh_b(a2[2][0], kb2[2]), tanh_b(a2[2][1], kb2[2])),
                   pk2(tanh_b(a2[2][2], kb2[2]), tanh_b(a2[2][3], kb2[2])),
                   pk2(tanh_b(a2[3][0], kb2[3]), tanh_b(a2[3][1], kb2[3])),
                   pk2(tanh_b(a2[3][2], kb2[3]), tanh_b(a2[3][3], kb2[3])));
    }
    {                                      // second half: W2 from LDS
      f32x4 a2[4];
      #pragma unroll
      for (int t2 = 0; t2 < 4; ++t2) {
        f32x4 acc = zc;
        #pragma unroll
        for (int kt = 0; kt < 4; ++kt) {
          sh8 wb = *(const sh8*)&lds.u.s.wfr[W2F + t2 * 4 + kt][lane][0];
          acc = MFMA(wb, h1f[kt], acc);
        }
        a2[t2] = acc;
      }
      h2f[2] = mk4(pk2(tanh_b(a2[0][0], kb2[4]), tanh_b(a2[0][1], kb2[4])),
                   pk2(tanh_b(a2[0][2], kb2[4]), tanh_b(a2[0][3], kb2[4])),
                   pk2(tanh_b(a2[1][0], kb2[5]), tanh_b(a2[1][1], kb2[5])),
                   pk2(tanh_b(a2[1][2], kb2[5]), tanh_b(a2[1][3], kb2[5])));
      h2f[3] = mk4(pk2(tanh_b(a2[2][0], kb2[6]), tanh_b(a2[2][1], kb2[6])),
                   pk2(tanh_b(a2[2][2], kb2[6]), tanh_b(a2[2][3], kb2[6])),
                   pk2(tanh_b(a2[3][0], kb2[7]), tanh_b(a2[3][1], kb2[7])),
                   pk2(tanh_b(a2[3][2], kb2[7]), tanh_b(a2[3][3], kb2[7])));
    }

    // ---- drift L3 (all-register) ----
    f32x4 accd = cd3v;
    #pragma unroll
    for (int kt = 0; kt < 4; ++kt)
      accd = MFMA(w3a[kt], h2f[kt], accd);

    // ---- EM update + vector store ----
    {
      float f0 = accf[0] * sdt, f1 = accf[1] * sdt;
      float f2 = accf[2] * sdt, f3 = accf[3] * sdt;
      zreg[0] = __builtin_fmaf(f0, eps0, __builtin_fmaf(accd[0], dtv, zreg[0]));
      zreg[1] = __builtin_fmaf(f1, eps1, __builtin_fmaf(accd[1], dtv, zreg[1]));
      zreg[2] = __builtin_fmaf(f2, eps2, __builtin_fmaf(accd[2], dtv, zreg[2]));
      zreg[3] = __builtin_fmaf(f3, eps3, __builtin_fmaf(accd[3], dtv, zreg[3]));
    }
    if (quad < 2) {
      *(f32x2*)op       = (f32x2){zreg[0], zreg[1]};
      *(f32x2*)(op + 2) = (f32x2){zreg[2], zreg[3]};
    } else if (quad == 2) {
      *(f32x2*)op       = (f32x2){zreg[0], zreg[1]};
    }
    op += (size_t)B_TOT * 10;
    zreg[2] = (quad == 2) ? tnext : zreg[2];   // refresh t feature
    tcur = tnext;
  }
}

extern "C" void kernel_launch(void* const* d_in, const int* in_sizes, int n_in,
                              void* d_out, int out_size, void* d_ws, size_t ws_size,
                              hipStream_t stream) {
  (void)in_sizes; (void)n_in; (void)d_ws; (void)ws_size; (void)out_size;
  const float* z0       = (const float*)d_in[0];
  const float* activity = (const float*)d_in[1];
  const float* rest     = (const float*)d_in[2];
  const float* ts       = (const float*)d_in[3];
  const float* noise    = (const float*)d_in[4];
  const float* aW1 = (const float*)d_in[5];
  const float* ab1 = (const float*)d_in[6];
  const float* aW2 = (const float*)d_in[7];
  const float* ab2 = (const float*)d_in[8];
  const float* rW1 = (const float*)d_in[9];
  const float* rb1 = (const float*)d_in[10];
  const float* rW2 = (const float*)d_in[11];
  const float* rb2 = (const float*)d_in[12];
  const float* dW1 = (const float*)d_in[13];
  const float* db1 = (const float*)d_in[14];
  const float* dW2 = (const float*)d_in[15];
  const float* db2 = (const float*)d_in[16];
  const float* dW3 = (const float*)d_in[17];
  const float* db3 = (const float*)d_in[18];
  const float* gW1 = (const float*)d_in[19];
  const float* gb1 = (const float*)d_in[20];
  const float* gW2 = (const float*)d_in[21];
  const float* gb2 = (const float*)d_in[22];
  float* out = (float*)d_out;

  dim3 grid(B_TOT / MT), block(256);
  sde_kernel<<<grid, block, 0, stream>>>(
      z0, activity, rest, ts, noise,
      aW1, ab1, aW2, ab2, rW1, rb1, rW2, rb2,
      dW1, db1, dW2, db2, dW3, db3,
      gW1, gb1, gW2, gb2, out);
}

// Round 5
// 556.849 us; speedup vs baseline: 1.9467x; 1.0404x over previous
//
#include <hip/hip_runtime.h>
#include <cstdint>
#include <cstddef>

// LatentNeuralSDE: 100 sequential EM steps, B=32768, LAT=10.
// R8: R7 structure + VALU instruction grind (kernel is VALU-throughput
// bound: VALU 61% + MFMA 15%). (1) tanh scale 2/ln2 folded into W1z/c1v
// and W2/c2v (db2*2.885 as MFMA C-init, +32 VGPR) -> activation is
// 1-2*rcp(exp2(y)+1), saving 64 mul/fma per lane-step. (2) bf16 packing
// via v_cvt_pk_bf16_f32 (1 instr, RTNE) instead of 3-op pk2 -> ~76 ops
// saved. W1 + W2 t2=4..7 in frag-linear LDS behind anti-LICM clobber;
// W2 t2=0..3 / W3 / G1 / G2 persistent in registers; no in-loop barriers.

#define B_TOT 32768
#define NSTEP 100
#define MT    64

typedef __attribute__((ext_vector_type(8))) short sh8;
typedef __attribute__((ext_vector_type(4))) float f32x4;
typedef __attribute__((ext_vector_type(2))) float f32x2;
typedef __attribute__((ext_vector_type(4))) unsigned int u32x4;

#define MFMA(a, b, c) __builtin_amdgcn_mfma_f32_16x16x32_bf16((a), (b), (c), 0, 0, 0)

#define SC 2.8853900817779268f   // 2/ln2

// fragment table layout in LDS
#define W1F 0            // 8 frags  (L1 z-part, t=0..7; pre-scaled by SC)
#define W2F 8            // 16 frags (t2=4..7, pre-scaled): W2F + (t2-4)*4 + kt
#define NFR 24

struct __align__(16) Lds {
  union {
    float ar[MT][100];               // encoder outputs (prologue only)
    struct {
      short wfr[NFR][64][8];         // frag-linear weight frags (conflict-free)
    } s;
  } u;                               // 25600 B
  float tsl[104];
};

static __device__ __forceinline__ short f2bf(float v) {  // RTNE (weights, one-time)
  unsigned u = __builtin_bit_cast(unsigned, v);
  u += 0x7fffu + ((u >> 16) & 1u);
  return (short)(u >> 16);
}
// 2 f32 -> packed 2x bf16 (RTNE), one HW instruction (no builtin on gfx950)
static __device__ __forceinline__ unsigned cvtpk(float lo, float hi) {
  unsigned r;
  asm("v_cvt_pk_bf16_f32 %0, %1, %2" : "=v"(r) : "v"(lo), "v"(hi));
  return r;
}
static __device__ __forceinline__ sh8 mk4(unsigned a, unsigned b, unsigned c, unsigned d) {
  return __builtin_bit_cast(sh8, (u32x4){a, b, c, d});
}
// tanh with the 2/ln2 scale pre-folded into the matmul: y = SC*(Wx+b)
static __device__ __forceinline__ float act_post(float y) {
  float e = __builtin_amdgcn_exp2f(y);
  float r = __builtin_amdgcn_rcpf(e + 1.0f);
  return __builtin_fmaf(-2.0f, r, 1.0f);
}
static __device__ __forceinline__ float softplus_fast(float x) {
  float e = __builtin_amdgcn_exp2f(x * 1.4426950408889634f);
  float l = __builtin_amdgcn_logf(e + 1.0f) * 0.6931471805599453f;
  return (x > 20.0f) ? x : l;
}

__global__ __launch_bounds__(256, 2)
void sde_kernel(const float* __restrict__ z0, const float* __restrict__ activity,
                const float* __restrict__ rest, const float* __restrict__ ts,
                const float* __restrict__ noise,
                const float* __restrict__ aW1, const float* __restrict__ ab1,
                const float* __restrict__ aW2, const float* __restrict__ ab2,
                const float* __restrict__ rW1, const float* __restrict__ rb1,
                const float* __restrict__ rW2, const float* __restrict__ rb2,
                const float* __restrict__ dW1, const float* __restrict__ db1,
                const float* __restrict__ dW2, const float* __restrict__ db2,
                const float* __restrict__ dW3, const float* __restrict__ db3,
                const float* __restrict__ gW1, const float* __restrict__ gb1,
                const float* __restrict__ gW2, const float* __restrict__ gb2,
                float* __restrict__ out)
{
  __shared__ Lds lds;
  const int tid  = threadIdx.x;
  const int lane = tid & 63;
  const int wave = tid >> 6;
  const int n    = lane & 15;   // batch col (B/D col) / A-row m in weight gathers
  const int quad = lane >> 4;
  const int slab = wave * 16;
  const int mblk = blockIdx.x * MT;
  const int rowg = mblk + slab + n;   // this lane's global batch row

  if (tid < 101) lds.tsl[tid] = ts[tid];
  float tcur = ts[0];

  // ---------------- encoders -> ar (wave-private rows) ----------------
  {
    const int e = tid >> 2, p = tid & 3;
    const int eg = mblk + e;
    float act[6], rst[3];
    #pragma unroll
    for (int i = 0; i < 6; ++i) act[i] = activity[eg * 6 + i];
    #pragma unroll
    for (int i = 0; i < 3; ++i) rst[i] = rest[eg * 3 + i];
    float ha[32];
    for (int j = 0; j < 32; ++j) {
      float s = ab1[j];
      #pragma unroll
      for (int i = 0; i < 6; ++i) s = __builtin_fmaf(act[i], aW1[i * 32 + j], s);
      ha[j] = fmaxf(s, 0.0f);
    }
    float hr[16];
    for (int j = 0; j < 16; ++j) {
      float s = rb1[j];
      #pragma unroll
      for (int i = 0; i < 3; ++i) s = __builtin_fmaf(rst[i], rW1[i * 16 + j], s);
      hr[j] = fmaxf(s, 0.0f);
    }
    for (int oo = 0; oo < 24; ++oo) {
      int o = p * 24 + oo;
      float v;
      if (o < 64) {
        v = ab2[o];
        for (int j = 0; j < 32; ++j) v = __builtin_fmaf(ha[j], aW2[j * 64 + o], v);
      } else {
        int ro = o - 64;
        v = rb2[ro];
        for (int j = 0; j < 16; ++j) v = __builtin_fmaf(hr[j], rW2[j * 32 + ro], v);
      }
      lds.u.ar[e][o] = v;
    }
  }
  // no barrier needed: each wave reads only its own 16 ar rows below.

  // ---------------- c1 context fold: c1[batch n][feat 16t+4q+r] ----------------
  f32x4 c1v[8];
  #pragma unroll
  for (int t = 0; t < 8; ++t)
    c1v[t] = *(const f32x4*)(db1 + t * 16 + quad * 4);
  for (int k = 0; k < 96; ++k) {
    float av = lds.u.ar[slab + n][k];
    #pragma unroll
    for (int t = 0; t < 8; ++t) {
      f32x4 w = *(const f32x4*)(dW1 + (10 + k) * 128 + t * 16 + quad * 4);
      #pragma unroll
      for (int r = 0; r < 4; ++r) c1v[t][r] = __builtin_fmaf(av, w[r], c1v[t][r]);
    }
  }
  // fold the tanh scale into c1 (matches SC-scaled W1z frags)
  #pragma unroll
  for (int t = 0; t < 8; ++t) {
    #pragma unroll
    for (int r = 0; r < 4; ++r) c1v[t][r] *= SC;
  }
  __syncthreads();   // ar dead everywhere; wfr (union) may now be written.

  // ---------------- weight A-frags (W^T, pi-permuted k) ----------------
  // pi: slot (quad,j) -> feature fbase + 16*(j>>2) + 4*quad + (j&3)
  // LDS frags: all waves write identical data; each wave's own writes are
  // visible to it in-order (no barrier needed).
  #pragma unroll
  for (int t = 0; t < 8; ++t) {            // L1 z-part -> LDS (K=16 real), SC-scaled
    short tmp[8];
    #pragma unroll
    for (int j = 0; j < 8; ++j) {
      float v = 0.0f;
      if (j < 4) {
        int f = 4 * quad + j;
        if (f < 10) v = dW1[f * 128 + t * 16 + n];
        else if (f == 10) v = dW1[106 * 128 + t * 16 + n];
      }
      tmp[j] = f2bf(SC * v);
    }
    *(sh8*)&lds.u.s.wfr[W1F + t][lane][0] =
        (sh8){tmp[0],tmp[1],tmp[2],tmp[3],tmp[4],tmp[5],tmp[6],tmp[7]};
  }
  sh8 w2a[4][4];                           // W2^T t2=0..3 regs, t2=4..7 LDS, SC-scaled
  #pragma unroll
  for (int t2 = 0; t2 < 8; ++t2) {
    #pragma unroll
    for (int kt = 0; kt < 4; ++kt) {
      short tmp[8];
      #pragma unroll
      for (int j = 0; j < 8; ++j) {
        int f = 32 * kt + 16 * (j >> 2) + 4 * quad + (j & 3);
        tmp[j] = f2bf(SC * dW2[f * 128 + t2 * 16 + n]);
      }
      sh8 fr = (sh8){tmp[0],tmp[1],tmp[2],tmp[3],tmp[4],tmp[5],tmp[6],tmp[7]};
      if (t2 < 4) w2a[t2][kt] = fr;
      else *(sh8*)&lds.u.s.wfr[W2F + (t2 - 4) * 4 + kt][lane][0] = fr;
    }
  }
  sh8 w3a[4];                              // W3^T regs: rows m>=10 zeroed (unscaled)
  #pragma unroll
  for (int kt = 0; kt < 4; ++kt) {
    short tmp[8];
    #pragma unroll
    for (int j = 0; j < 8; ++j) {
      int f = 32 * kt + 16 * (j >> 2) + 4 * quad + (j & 3);
      tmp[j] = f2bf((n < 10) ? dW3[f * 10 + n] : 0.0f);
    }
    w3a[kt] = (sh8){tmp[0],tmp[1],tmp[2],tmp[3],tmp[4],tmp[5],tmp[6],tmp[7]};
  }
  sh8 g1a[2];                              // G1^T regs: K=16 real (unscaled)
  #pragma unroll
  for (int t = 0; t < 2; ++t) {
    short tmp[8];
    #pragma unroll
    for (int j = 0; j < 8; ++j) {
      float v = 0.0f;
      if (j < 4) {
        int f = 4 * quad + j;
        if (f < 10) v = gW1[f * 32 + t * 16 + n];
        else if (f == 10) v = gW1[10 * 32 + t * 16 + n];
      }
      tmp[j] = f2bf(v);
    }
    g1a[t] = (sh8){tmp[0],tmp[1],tmp[2],tmp[3],tmp[4],tmp[5],tmp[6],tmp[7]};
  }
  sh8 g2a;                                 // G2^T reg: K=32 (both halves real)
  {
    short tmp[8];
    #pragma unroll
    for (int j = 0; j < 8; ++j) {
      int h = 16 * (j >> 2) + 4 * quad + (j & 3);
      tmp[j] = f2bf((n < 10) ? gW2[h * 10 + n] : 0.0f);
    }
    g2a = (sh8){tmp[0],tmp[1],tmp[2],tmp[3],tmp[4],tmp[5],tmp[6],tmp[7]};
  }

  // ---------------- bias folds (D layout: row = 4q + r) ----------------
  f32x4 c2v[8];                            // SC * db2 as L2 MFMA C-init
  #pragma unroll
  for (int t2 = 0; t2 < 8; ++t2) {
    #pragma unroll
    for (int r = 0; r < 4; ++r)
      c2v[t2][r] = SC * db2[t2 * 16 + quad * 4 + r];
  }
  f32x4 cd3v, cg1v0, cg1v1, cg2v;
  #pragma unroll
  for (int r = 0; r < 4; ++r) {
    int o = quad * 4 + r;
    cd3v[r]  = (o < 10) ? db3[o] : 0.0f;
    cg1v0[r] = gb1[o];
    cg1v1[r] = gb1[16 + o];
    cg2v[r]  = (o < 10) ? gb2[o] : 0.0f;
  }

  // ---------------- z init (registers, D layout), out[0] ----------------
  float zreg[4] = {0.0f, 0.0f, 0.0f, 0.0f};
  {
    const float* zp = z0 + (size_t)rowg * 10 + quad * 4;
    float* o0 = out + (size_t)rowg * 10 + quad * 4;
    if (quad < 2) {
      f32x2 a = *(const f32x2*)zp, b = *(const f32x2*)(zp + 2);
      zreg[0] = a.x; zreg[1] = a.y; zreg[2] = b.x; zreg[3] = b.y;
      *(f32x2*)o0 = a; *(f32x2*)(o0 + 2) = b;
    } else if (quad == 2) {
      f32x2 a = *(const f32x2*)zp;
      zreg[0] = a.x; zreg[1] = a.y;
      *(f32x2*)o0 = a;
      zreg[2] = tcur;               // feature 10 = t; feature 11 stays 0
    }
  }
  const float* np = noise + (size_t)rowg * 10 + quad * 4;
  float*       op = out + (size_t)B_TOT * 10 + (size_t)rowg * 10 + quad * 4;

  #pragma unroll 1
  for (int s = 0; s < NSTEP; ++s) {
    // Anti-LICM: keep the remaining LDS frag reads in-loop (R5 lesson).
    asm volatile("" ::: "memory");

    float tnext = lds.tsl[s + 1];
    float dtv   = tnext - tcur;
    float sdt   = __builtin_amdgcn_sqrtf(dtv);

    // noise prefetch (vector, used at step end)
    float eps0 = 0.0f, eps1 = 0.0f, eps2 = 0.0f, eps3 = 0.0f;
    if (quad < 2) {
      f32x2 a = *(const f32x2*)np, b = *(const f32x2*)(np + 2);
      eps0 = a.x; eps1 = a.y; eps2 = b.x; eps3 = b.y;
    } else if (quad == 2) {
      f32x2 a = *(const f32x2*)np;
      eps0 = a.x; eps1 = a.y;
    }
    np += (size_t)B_TOT * 10;

    // W1 frag reads issued early; latency hides under diffusion (reg frags)
    sh8 w1v[8];
    #pragma unroll
    for (int t = 0; t < 8; ++t)
      w1v[t] = *(const sh8*)&lds.u.s.wfr[W1F + t][lane][0];

    // z B-frag (k = 4q + r via pi; upper half zero-weighted)
    sh8 zf = mk4(cvtpk(zreg[0], zreg[1]), cvtpk(zreg[2], zreg[3]), 0u, 0u);

    // ---- diffusion: hg = softplus(zt @ G1), accf = hg @ G2 (all-register) ----
    f32x4 accf;
    {
      f32x4 g0 = MFMA(g1a[0], zf, cg1v0);
      f32x4 g1 = MFMA(g1a[1], zf, cg1v1);
      sh8 gb = mk4(cvtpk(softplus_fast(g0[0]), softplus_fast(g0[1])),
                   cvtpk(softplus_fast(g0[2]), softplus_fast(g0[3])),
                   cvtpk(softplus_fast(g1[0]), softplus_fast(g1[1])),
                   cvtpk(softplus_fast(g1[2]), softplus_fast(g1[3])));
      accf = MFMA(g2a, gb, cg2v);
    }

    // ---- drift L1: h1 = tanh(zt @ W1z + c1); scale folded into W1z/c1 ----
    sh8 h1f[4];
    #pragma unroll
    for (int kt = 0; kt < 4; ++kt) {
      f32x4 ae = MFMA(w1v[2 * kt],     zf, c1v[2 * kt]);
      f32x4 ao = MFMA(w1v[2 * kt + 1], zf, c1v[2 * kt + 1]);
      h1f[kt] = mk4(cvtpk(act_post(ae[0]), act_post(ae[1])),
                    cvtpk(act_post(ae[2]), act_post(ae[3])),
                    cvtpk(act_post(ao[0]), act_post(ao[1])),
                    cvtpk(act_post(ao[2]), act_post(ao[3])));
    }

    // ---- drift L2: h2 = tanh(h1 @ W2 + db2); scale folded into W2/c2v ----
    sh8 h2f[4];
    {                                      // first half: W2 in registers
      f32x4 a2[4];
      #pragma unroll
      for (int t2 = 0; t2 < 4; ++t2) {
        f32x4 acc = c2v[t2];
        #pragma unroll
        for (int kt = 0; kt < 4; ++kt)
          acc = MFMA(w2a[t2][kt], h1f[kt], acc);
        a2[t2] = acc;
      }
      h2f[0] = mk4(cvtpk(act_post(a2[0][0]), act_post(a2[0][1])),
                   cvtpk(act_post(a2[0][2]), act_post(a2[0][3])),
                   cvtpk(act_post(a2[1][0]), act_post(a2[1][1])),
                   cvtpk(act_post(a2[1][2]), act_post(a2[1][3])));
      h2f[1] = mk4(cvtpk(act_post(a2[2][0]), act_post(a2[2][1])),
                   cvtpk(act_post(a2[2][2]), act_post(a2[2][3])),
                   cvtpk(act_post(a2[3][0]), act_post(a2[3][1])),
                   cvtpk(act_post(a2[3][2]), act_post(a2[3][3])));
    }
    {                                      // second half: W2 from LDS
      f32x4 a2[4];
      #pragma unroll
      for (int t2 = 0; t2 < 4; ++t2) {
        f32x4 acc = c2v[t2 + 4];
        #pragma unroll
        for (int kt = 0; kt < 4; ++kt) {
          sh8 wb = *(const sh8*)&lds.u.s.wfr[W2F + t2 * 4 + kt][lane][0];
          acc = MFMA(wb, h1f[kt], acc);
        }
        a2[t2] = acc;
      }
      h2f[2] = mk4(cvtpk(act_post(a2[0][0]), act_post(a2[0][1])),
                   cvtpk(act_post(a2[0][2]), act_post(a2[0][3])),
                   cvtpk(act_post(a2[1][0]), act_post(a2[1][1])),
                   cvtpk(act_post(a2[1][2]), act_post(a2[1][3])));
      h2f[3] = mk4(cvtpk(act_post(a2[2][0]), act_post(a2[2][1])),
                   cvtpk(act_post(a2[2][2]), act_post(a2[2][3])),
                   cvtpk(act_post(a2[3][0]), act_post(a2[3][1])),
                   cvtpk(act_post(a2[3][2]), act_post(a2[3][3])));
    }

    // ---- drift L3 (all-register) ----
    f32x4 accd = cd3v;
    #pragma unroll
    for (int kt = 0; kt < 4; ++kt)
      accd = MFMA(w3a[kt], h2f[kt], accd);

    // ---- EM update + vector store ----
    {
      float f0 = accf[0] * sdt, f1 = accf[1] * sdt;
      float f2 = accf[2] * sdt, f3 = accf[3] * sdt;
      zreg[0] = __builtin_fmaf(f0, eps0, __builtin_fmaf(accd[0], dtv, zreg[0]));
      zreg[1] = __builtin_fmaf(f1, eps1, __builtin_fmaf(accd[1], dtv, zreg[1]));
      zreg[2] = __builtin_fmaf(f2, eps2, __builtin_fmaf(accd[2], dtv, zreg[2]));
      zreg[3] = __builtin_fmaf(f3, eps3, __builtin_fmaf(accd[3], dtv, zreg[3]));
    }
    if (quad < 2) {
      *(f32x2*)op       = (f32x2){zreg[0], zreg[1]};
      *(f32x2*)(op + 2) = (f32x2){zreg[2], zreg[3]};
    } else if (quad == 2) {
      *(f32x2*)op       = (f32x2){zreg[0], zreg[1]};
    }
    op += (size_t)B_TOT * 10;
    zreg[2] = (quad == 2) ? tnext : zreg[2];   // refresh t feature
    tcur = tnext;
  }
}

extern "C" void kernel_launch(void* const* d_in, const int* in_sizes, int n_in,
                              void* d_out, int out_size, void* d_ws, size_t ws_size,
                              hipStream_t stream) {
  (void)in_sizes; (void)n_in; (void)d_ws; (void)ws_size; (void)out_size;
  const float* z0       = (const float*)d_in[0];
  const float* activity = (const float*)d_in[1];
  const float* rest     = (const float*)d_in[2];
  const float* ts       = (const float*)d_in[3];
  const float* noise    = (const float*)d_in[4];
  const float* aW1 = (const float*)d_in[5];
  const float* ab1 = (const float*)d_in[6];
  const float* aW2 = (const float*)d_in[7];
  const float* ab2 = (const float*)d_in[8];
  const float* rW1 = (const float*)d_in[9];
  const float* rb1 = (const float*)d_in[10];
  const float* rW2 = (const float*)d_in[11];
  const float* rb2 = (const float*)d_in[12];
  const float* dW1 = (const float*)d_in[13];
  const float* db1 = (const float*)d_in[14];
  const float* dW2 = (const float*)d_in[15];
  const float* db2 = (const float*)d_in[16];
  const float* dW3 = (const float*)d_in[17];
  const float* db3 = (const float*)d_in[18];
  const float* gW1 = (const float*)d_in[19];
  const float* gb1 = (const float*)d_in[20];
  const float* gW2 = (const float*)d_in[21];
  const float* gb2 = (const float*)d_in[22];
  float* out = (float*)d_out;

  dim3 grid(B_TOT / MT), block(256);
  sde_kernel<<<grid, block, 0, stream>>>(
      z0, activity, rest, ts, noise,
      aW1, ab1, aW2, ab2, rW1, rb1, rW2, rb2,
      dW1, db1, dW2, db2, dW3, db3,
      gW1, gb1, gW2, gb2, out);
}